// Round 10
// baseline (476.471 us; speedup 1.0000x reference)
//
#include <hip/hip_runtime.h>
#include <hip/hip_bf16.h>

#define D_   1024
#define NH_  16
#define DH_  64
#define T_   2048
#define S_   2048
#define B_   2
#define FF_  4096

typedef __bf16 bf16x8 __attribute__((ext_vector_type(8)));
typedef float  f32x4  __attribute__((ext_vector_type(4)));
typedef unsigned int u32x4 __attribute__((ext_vector_type(4)));

static __device__ __forceinline__ unsigned short f2bf(float f) {
    union { float f; unsigned int i; } v; v.f = f;
    unsigned int x = v.i;
    return (unsigned short)((x + 0x7fffu + ((x >> 16) & 1u)) >> 16);
}
static __device__ __forceinline__ float fexp2(float x) {
    return __builtin_amdgcn_exp2f(x);          // raw v_exp_f32 (fast, 1 VALU op)
}

// async global->LDS, 16B per lane; LDS dest is wave-uniform base + lane*16
static __device__ __forceinline__ void gld16(const unsigned short* g, unsigned short* l) {
    __builtin_amdgcn_global_load_lds(
        (const __attribute__((address_space(1))) void*)g,
        (__attribute__((address_space(3))) void*)l, 16, 0, 0);
}

// ---------------- weight transpose: W[K][N] f32 -> Wt[N][K] bf16 ----------------
__global__ __launch_bounds__(256) void transpose_w(const float* __restrict__ W,
                                                   unsigned short* __restrict__ Wt,
                                                   int K, int N) {
    __shared__ float tile[32][33];
    int n0 = blockIdx.x * 32, k0 = blockIdx.y * 32;
    int c = threadIdx.x & 31, r0 = threadIdx.x >> 5;
    #pragma unroll
    for (int i = 0; i < 4; ++i) {
        int r = r0 + i * 8;
        tile[r][c] = W[(size_t)(k0 + r) * N + n0 + c];
    }
    __syncthreads();
    #pragma unroll
    for (int i = 0; i < 4; ++i) {
        int r = r0 + i * 8;
        Wt[(size_t)(n0 + r) * K + k0 + c] = f2bf(tile[c][r]);
    }
}

// ---------------- LayerNorm (row of 1024 f32) -> bf16 ----------------
__global__ __launch_bounds__(256) void ln_bf16(const float* __restrict__ x,
                                               const float* __restrict__ g,
                                               const float* __restrict__ b,
                                               unsigned short* __restrict__ out) {
    int row = blockIdx.x;
    int t = threadIdx.x;
    const float4* xr = (const float4*)(x + (size_t)row * D_);
    float4 v = xr[t];
    float s = v.x + v.y + v.z + v.w;
    float s2 = v.x*v.x + v.y*v.y + v.z*v.z + v.w*v.w;
    #pragma unroll
    for (int o = 32; o > 0; o >>= 1) { s += __shfl_down(s, o); s2 += __shfl_down(s2, o); }
    __shared__ float red[8];
    int wid = t >> 6, lane = t & 63;
    if (lane == 0) { red[wid*2] = s; red[wid*2+1] = s2; }
    __syncthreads();
    float ts  = red[0] + red[2] + red[4] + red[6];
    float ts2 = red[1] + red[3] + red[5] + red[7];
    float mu = ts * (1.0f / D_);
    float var = ts2 * (1.0f / D_) - mu * mu;
    float rstd = rsqrtf(var + 1e-5f);
    float4 gv = ((const float4*)g)[t];
    float4 bv = ((const float4*)b)[t];
    ushort4 o4;
    o4.x = f2bf((v.x - mu) * rstd * gv.x + bv.x);
    o4.y = f2bf((v.y - mu) * rstd * gv.y + bv.y);
    o4.z = f2bf((v.z - mu) * rstd * gv.z + bv.z);
    o4.w = f2bf((v.w - mu) * rstd * gv.w + bv.w);
    ((ushort4*)(out + (size_t)row * D_))[t] = o4;
}

// ---------------- f32 -> bf16 convert ----------------
__global__ __launch_bounds__(256) void cvt_f32_bf16(const float* __restrict__ in,
                                                    unsigned short* __restrict__ out, int n4) {
    int i = blockIdx.x * 256 + threadIdx.x;
    if (i < n4) {
        float4 v = ((const float4*)in)[i];
        ushort4 o; o.x = f2bf(v.x); o.y = f2bf(v.y); o.z = f2bf(v.z); o.w = f2bf(v.w);
        ((ushort4*)out)[i] = o;
    }
}

// ---------------- GEMM: C[M][N] = A[M][K](bf16) @ Bt[N][K]^T (bf16) ----------------
// m97 structure + L2 rasterization (unchanged — verified round 5/6).
template<int EPI>
__global__ __launch_bounds__(256) void gemm_bt(const unsigned short* __restrict__ A,
                                               const unsigned short* __restrict__ Bt,
                                               float* __restrict__ Cf,
                                               unsigned short* __restrict__ Cb,
                                               const float* __restrict__ bias,
                                               const float* __restrict__ resid,
                                               int M, int N, int K, int gn, int nb) {
    __shared__ unsigned short As[128 * 32];
    __shared__ unsigned short Bs[128 * 32];
    int tid = threadIdx.x;
    int lane = tid & 63, wv = tid >> 6;
    int wm = wv >> 1, wn = wv & 1;
    int lr = lane & 15, lg = lane >> 4;

    int bid = blockIdx.x, nwg = gridDim.x;
    int q8 = nwg >> 3, r8 = nwg & 7;
    int xcd = bid & 7, idx = bid >> 3;
    int wg = (xcd < r8 ? xcd * (q8 + 1) : r8 * (q8 + 1) + (xcd - r8) * q8) + idx;
    int gm = nwg / gn;
    int bandsz = gm * nb;
    int band = wg / bandsz;
    int rem = wg - band * bandsz;
    int mt = rem / nb;
    int nt = band * nb + (rem - mt * nb);
    int m0 = mt * 128, n0 = nt * 128;

    int csw = ((lane & 3) ^ ((lane >> 3) & 3)) * 8;
    const unsigned short* aSrc[2];
    const unsigned short* bSrc[2];
    unsigned short* aDst[2];
    unsigned short* bDst[2];
    #pragma unroll
    for (int i = 0; i < 2; ++i) {
        int rblk = wv * 2 + i;
        int row = rblk * 16 + (lane >> 2);
        aSrc[i] = A  + (size_t)(m0 + row) * K + csw;
        bSrc[i] = Bt + (size_t)(n0 + row) * K + csw;
        aDst[i] = &As[rblk * 512];
        bDst[i] = &Bs[rblk * 512];
    }

    const f32x4 vzero = {0.f, 0.f, 0.f, 0.f};
    f32x4 acc[4][4];
    #pragma unroll
    for (int i = 0; i < 4; ++i)
        #pragma unroll
        for (int j = 0; j < 4; ++j) acc[i][j] = vzero;

    for (int k0 = 0; k0 < K; k0 += 32) {
        __syncthreads();
        #pragma unroll
        for (int i = 0; i < 2; ++i) {
            gld16(aSrc[i] + k0, aDst[i]);
            gld16(bSrc[i] + k0, bDst[i]);
        }
        __syncthreads();
        bf16x8 a[4], b[4];
        #pragma unroll
        for (int f = 0; f < 4; ++f) {
            int ra = wm * 64 + f * 16 + lr;
            a[f] = __builtin_bit_cast(bf16x8, *(const u32x4*)&As[ra * 32 + ((lg ^ ((ra >> 1) & 3)) << 3)]);
            int rb = wn * 64 + f * 16 + lr;
            b[f] = __builtin_bit_cast(bf16x8, *(const u32x4*)&Bs[rb * 32 + ((lg ^ ((rb >> 1) & 3)) << 3)]);
        }
        #pragma unroll
        for (int i = 0; i < 4; ++i)
            #pragma unroll
            for (int j = 0; j < 4; ++j)
                acc[i][j] = __builtin_amdgcn_mfma_f32_16x16x32_bf16(a[i], b[j], acc[i][j], 0, 0, 0);
    }

    #pragma unroll
    for (int i = 0; i < 4; ++i) {
        int rbase = m0 + wm * 64 + i * 16 + lg * 4;
        #pragma unroll
        for (int j = 0; j < 4; ++j) {
            int col = n0 + wn * 64 + j * 16 + lr;
            #pragma unroll
            for (int r = 0; r < 4; ++r) {
                int row = rbase + r;
                float v = acc[i][j][r];
                if (EPI == 0) {
                    Cb[(size_t)row * N + col] = f2bf(v);
                } else if (EPI == 1) {
                    v += bias[col];
                    v = v > 0.f ? v : 0.f;
                    Cb[(size_t)row * N + col] = f2bf(v);
                } else {
                    v += bias[col] + resid[(size_t)row * N + col];
                    Cf[(size_t)row * N + col] = v;
                }
            }
        }
    }
}

// ---------------- MFMA flash attention, 32 q-rows per wave (2 groups of 16) ----------------
// Round-6 verified structure (P via per-wave LDS, straight QK^T). Only change: fast exp2
// via __builtin_amdgcn_exp2f (raw v_exp_f32) instead of OCML exp2f.
// NOTE: launch_bounds MUST stay (256,2) — unified VGPR+AGPR need ~160/wave; higher
// min-waves caps regs below need and spills (round3 (256,6)=435us; round5 (256,4)=295us).
template<bool CAUSAL>
__global__ __launch_bounds__(256, 2) void attn_mfma(
    const unsigned short* __restrict__ Qsrc, int q_stride,
    const unsigned short* __restrict__ KVsrc, int kv_stride,
    int k_off0, int v_off0,
    unsigned short* __restrict__ Y, int Lk)
{
    __shared__ unsigned short Kl[64 * 64];        // [key][dh], chunk c=dh>>3 at c^(key&7)
    __shared__ unsigned short Vt[64 * 64];        // [dh][key], chunk c=key>>3 at c^(dh&7)
    __shared__ unsigned short Pl[4][2][16 * 64];  // per-wave, per-group [q][key], chunk c^(q&7)

    const float SCL = 0.125f * 1.44269504f;       // 1/sqrt(DH) * log2(e)

    const int tid = threadIdx.x;
    const int lane = tid & 63, w = tid >> 6;
    const int lr = lane & 15, lg = lane >> 4;
    const int h = blockIdx.y, b = blockIdx.z;
    const int bx = blockIdx.x;

    int qw[2];
    if (CAUSAL) {
        qw[0] = bx * 64 + w * 16;
        qw[1] = (2 * (int)gridDim.x - 1 - bx) * 64 + w * 16;
    } else {
        qw[0] = bx * 128 + w * 16;
        qw[1] = bx * 128 + 64 + w * 16;
    }
    const int ntiles = CAUSAL ? (2 * (int)gridDim.x - bx) : (Lk / 64);

    bf16x8 qf[2][2];
    #pragma unroll
    for (int g = 0; g < 2; ++g) {
        const unsigned short* qp = Qsrc + ((size_t)(b * T_) + qw[g] + lr) * q_stride + h * DH_ + lg * 8;
        qf[g][0] = __builtin_bit_cast(bf16x8, *(const u32x4*)qp);
        qf[g][1] = __builtin_bit_cast(bf16x8, *(const u32x4*)(qp + 32));
    }
    bf16x8 onesf;
    #pragma unroll
    for (int i = 0; i < 8; ++i) onesf[i] = (__bf16)1.0f;

    f32x4 o[2][4];
    f32x4 accl[2];
    float mrow[2][4];                 // running max in log2 domain
    #pragma unroll
    for (int g = 0; g < 2; ++g) {
        #pragma unroll
        for (int f = 0; f < 4; ++f) o[g][f] = {0.f, 0.f, 0.f, 0.f};
        accl[g] = {0.f, 0.f, 0.f, 0.f};
        #pragma unroll
        for (int r = 0; r < 4; ++r) mrow[g][r] = -3e38f;
    }

    // staging thread mappings (block-constant)
    const int kkey = tid >> 2, kdc = (tid & 3) * 2;   // K: 4 threads/key, 2x16B chunks each
    const unsigned short* kbase = KVsrc + ((size_t)(b * Lk) + kkey) * kv_stride + k_off0 + h * DH_ + kdc * 8;
    const int vkey = lane;                            // V: key per lane; wave w -> dh chunks {w, w+4}
    const unsigned short* vbase = KVsrc + ((size_t)(b * Lk) + vkey) * kv_stride + v_off0 + h * DH_;

    u32x4 kr0 = *(const u32x4*)kbase;
    u32x4 kr1 = *(const u32x4*)(kbase + 8);
    u32x4 vr0 = *(const u32x4*)(vbase + w * 8);
    u32x4 vr1 = *(const u32x4*)(vbase + (w + 4) * 8);

    for (int t = 0; t < ntiles; ++t) {
        const int k0 = t * 64;
        __syncthreads();
        // ---- write staged registers to LDS ----
        {
            int s0 = (kdc    ) ^ (kkey & 7);
            int s1 = (kdc + 1) ^ (kkey & 7);
            *(u32x4*)&Kl[kkey * 64 + s0 * 8] = kr0;
            *(u32x4*)&Kl[kkey * 64 + s1 * 8] = kr1;
        }
        {
            const unsigned short* u0 = (const unsigned short*)&vr0;
            const unsigned short* u1 = (const unsigned short*)&vr1;
            int khi = vkey >> 3, klo = vkey & 7;
            #pragma unroll
            for (int j = 0; j < 8; ++j) {
                Vt[(w * 8 + j)       * 64 + ((khi ^ j) << 3) + klo] = u0[j];
                Vt[((w + 4) * 8 + j) * 64 + ((khi ^ j) << 3) + klo] = u1[j];
            }
        }
        __syncthreads();
        // ---- prefetch next tile into registers ----
        if (t + 1 < ntiles) {
            const unsigned short* kp = kbase + (size_t)(k0 + 64) * kv_stride;
            kr0 = *(const u32x4*)kp;
            kr1 = *(const u32x4*)(kp + 8);
            const unsigned short* vp = vbase + (size_t)(k0 + 64) * kv_stride;
            vr0 = *(const u32x4*)(vp + w * 8);
            vr1 = *(const u32x4*)(vp + (w + 4) * 8);
        }
        const bool act0 = !CAUSAL || (t <= bx);   // group1 always active

        // ---- QK^T for both groups, sharing each K-fragment read ----
        f32x4 s[2][4];
        #pragma unroll
        for (int g = 0; g < 2; ++g)
            #pragma unroll
            for (int f = 0; f < 4; ++f) s[g][f] = {0.f, 0.f, 0.f, 0.f};
        __builtin_amdgcn_s_setprio(1);
        #pragma unroll
        for (int ck = 0; ck < 2; ++ck) {
            int kc = lg + 4 * ck;
            #pragma unroll
            for (int f = 0; f < 4; ++f) {
                int key = f * 16 + lr;
                bf16x8 kb = __builtin_bit_cast(bf16x8,
                    *(const u32x4*)&Kl[key * 64 + ((kc ^ (key & 7)) << 3)]);
                if (act0) s[0][f] = __builtin_amdgcn_mfma_f32_16x16x32_bf16(qf[0][ck], kb, s[0][f], 0, 0, 0);
                s[1][f] = __builtin_amdgcn_mfma_f32_16x16x32_bf16(qf[1][ck], kb, s[1][f], 0, 0, 0);
            }
        }
        __builtin_amdgcn_s_setprio(0);

        // ---- per-group: mask, online softmax (log2 domain, defer-max), P pack+store ----
        #pragma unroll
        for (int g = 0; g < 2; ++g) {
            if (g == 0 && !act0) continue;
            if (CAUSAL && (k0 + 63 > qw[g])) {
                int dq = qw[g] + lg * 4 - k0 - lr;   // mask if f*16 - r > dq
                #pragma unroll
                for (int f = 0; f < 4; ++f)
                    #pragma unroll
                    for (int r = 0; r < 4; ++r)
                        s[g][f][r] = (f * 16 - r > dq) ? -3e38f : s[g][f][r];
            }
            float mx2[4];
            #pragma unroll
            for (int r = 0; r < 4; ++r) {
                float mx = fmaxf(fmaxf(s[g][0][r], s[g][1][r]), fmaxf(s[g][2][r], s[g][3][r]));
                mx = fmaxf(mx, __shfl_xor(mx, 1));
                mx = fmaxf(mx, __shfl_xor(mx, 2));
                mx = fmaxf(mx, __shfl_xor(mx, 4));
                mx = fmaxf(mx, __shfl_xor(mx, 8));
                mx2[r] = mx * SCL;
            }
            bool need = false;
            #pragma unroll
            for (int r = 0; r < 4; ++r) need = need || (mx2[r] > mrow[g][r] + 8.0f);
            if (__any(need ? 1 : 0)) {
                float corr[4];
                #pragma unroll
                for (int r = 0; r < 4; ++r) {
                    float mn = fmaxf(mrow[g][r], mx2[r]);
                    corr[r] = fexp2(mrow[g][r] - mn);
                    mrow[g][r] = mn;
                }
                #pragma unroll
                for (int f = 0; f < 4; ++f)
                    #pragma unroll
                    for (int r = 0; r < 4; ++r) o[g][f][r] *= corr[r];
                #pragma unroll
                for (int r = 0; r < 4; ++r) accl[g][r] *= corr[r];
            }
            unsigned short* pw = &Pl[w][g][0];
            #pragma unroll
            for (int f = 0; f < 4; ++f) {
                int key = f * 16 + lr;
                int khi2 = key >> 3, klo2 = key & 7;
                #pragma unroll
                for (int r = 0; r < 4; ++r) {
                    float p = fexp2(s[g][f][r] * SCL - mrow[g][r]);
                    union { float f; unsigned int i; } cv; cv.f = p;
                    int q = lg * 4 + r;
                    pw[q * 64 + ((khi2 ^ (q & 7)) << 3) + klo2] =
                        (unsigned short)((cv.i + 0x8000u) >> 16);
                }
            }
        }

        // ---- PV + row-sum, sharing each V-fragment read across groups ----
        __builtin_amdgcn_s_setprio(1);
        #pragma unroll
        for (int ck = 0; ck < 2; ++ck) {
            int kc = lg + 4 * ck;
            bf16x8 pa0, pa1;
            if (act0) {
                pa0 = __builtin_bit_cast(bf16x8,
                    *(const u32x4*)&Pl[w][0][lr * 64 + ((kc ^ (lr & 7)) << 3)]);
                accl[0] = __builtin_amdgcn_mfma_f32_16x16x32_bf16(pa0, onesf, accl[0], 0, 0, 0);
            }
            pa1 = __builtin_bit_cast(bf16x8,
                *(const u32x4*)&Pl[w][1][lr * 64 + ((kc ^ (lr & 7)) << 3)]);
            accl[1] = __builtin_amdgcn_mfma_f32_16x16x32_bf16(pa1, onesf, accl[1], 0, 0, 0);
            #pragma unroll
            for (int f = 0; f < 4; ++f) {
                int dh = f * 16 + lr;
                bf16x8 vb = __builtin_bit_cast(bf16x8,
                    *(const u32x4*)&Vt[dh * 64 + ((kc ^ (dh & 7)) << 3)]);
                if (act0) o[0][f] = __builtin_amdgcn_mfma_f32_16x16x32_bf16(pa0, vb, o[0][f], 0, 0, 0);
                o[1][f] = __builtin_amdgcn_mfma_f32_16x16x32_bf16(pa1, vb, o[1][f], 0, 0, 0);
            }
        }
        __builtin_amdgcn_s_setprio(0);
    }

    // ---- epilogue (both groups) ----
    #pragma unroll
    for (int g = 0; g < 2; ++g) {
        float inv[4];
        #pragma unroll
        for (int r = 0; r < 4; ++r) inv[r] = 1.f / accl[g][r];
        #pragma unroll
        for (int f = 0; f < 4; ++f)
            #pragma unroll
            for (int r = 0; r < 4; ++r) {
                float v = o[g][f][r] * inv[r];
                Y[((size_t)(b * T_) + qw[g] + lg * 4 + r) * D_ + h * DH_ + f * 16 + lr] = f2bf(v);
            }
    }
}

extern "C" void kernel_launch(void* const* d_in, const int* in_sizes, int n_in,
                              void* d_out, int out_size, void* d_ws, size_t ws_size,
                              hipStream_t stream) {
    const float* x        = (const float*)d_in[0];
    const float* ctx      = (const float*)d_in[1];
    const float* W_qkv    = (const float*)d_in[2];
    const float* W_out_sa = (const float*)d_in[3];
    const float* b_out_sa = (const float*)d_in[4];
    const float* W_q      = (const float*)d_in[5];
    const float* W_kv     = (const float*)d_in[6];
    const float* W_out_ca = (const float*)d_in[7];
    const float* b_out_ca = (const float*)d_in[8];
    const float* W1       = (const float*)d_in[9];
    const float* b1       = (const float*)d_in[10];
    const float* W2       = (const float*)d_in[11];
    const float* b2       = (const float*)d_in[12];
    const float* g1  = (const float*)d_in[13];
    const float* bb1 = (const float*)d_in[14];
    const float* g2  = (const float*)d_in[15];
    const float* bb2 = (const float*)d_in[16];
    const float* g3  = (const float*)d_in[17];
    const float* bb3 = (const float*)d_in[18];

    char* ws = (char*)d_ws;
    size_t off = 0;
    auto alloc = [&](size_t bytes) { char* p = ws + off; off += (bytes + 255) & ~(size_t)255; return p; };

    unsigned short* wqkv_t = (unsigned short*)alloc(3072UL * 1024 * 2);
    unsigned short* wosa_t = (unsigned short*)alloc(1024UL * 1024 * 2);
    unsigned short* wq_t   = (unsigned short*)alloc(1024UL * 1024 * 2);
    unsigned short* wkv_t  = (unsigned short*)alloc(2048UL * 1024 * 2);
    unsigned short* woca_t = (unsigned short*)alloc(1024UL * 1024 * 2);
    unsigned short* w1_t   = (unsigned short*)alloc(4096UL * 1024 * 2);
    unsigned short* w2_t   = (unsigned short*)alloc(1024UL * 4096 * 2);
    unsigned short* h_bf   = (unsigned short*)alloc(4096UL * 1024 * 2);
    float*          x1     = (float*)alloc(4096UL * 1024 * 4);
    unsigned short* y_bf   = (unsigned short*)alloc(4096UL * 1024 * 2);
    unsigned short* qkv_bf = (unsigned short*)alloc(4096UL * 3072 * 2);
    unsigned short* qca_bf = (unsigned short*)alloc(4096UL * 1024 * 2);
    unsigned short* kv_bf  = (unsigned short*)alloc(4096UL * 2048 * 2);
    unsigned short* hc_bf  = (unsigned short*)alloc(4096UL * 1024 * 2);
    unsigned short* m1_bf  = qkv_bf;   // reuse: qkv+qca regions dead by MLP
    float* x2 = (float*)d_out;

    // weight transposes (f32 KxN -> bf16 NxK)
    transpose_w<<<dim3(3072/32, 1024/32), 256, 0, stream>>>(W_qkv,    wqkv_t, 1024, 3072);
    transpose_w<<<dim3(1024/32, 1024/32), 256, 0, stream>>>(W_out_sa, wosa_t, 1024, 1024);
    transpose_w<<<dim3(1024/32, 1024/32), 256, 0, stream>>>(W_q,      wq_t,   1024, 1024);
    transpose_w<<<dim3(2048/32, 1024/32), 256, 0, stream>>>(W_kv,     wkv_t,  1024, 2048);
    transpose_w<<<dim3(1024/32, 1024/32), 256, 0, stream>>>(W_out_ca, woca_t, 1024, 1024);
    transpose_w<<<dim3(4096/32, 1024/32), 256, 0, stream>>>(W1,       w1_t,   1024, 4096);
    transpose_w<<<dim3(1024/32, 4096/32), 256, 0, stream>>>(W2,       w2_t,   4096, 1024);

    // --- self-attention block ---
    ln_bf16<<<4096, 256, 0, stream>>>(x, g1, bb1, h_bf);
    gemm_bt<0><<<768, 256, 0, stream>>>(h_bf, wqkv_t, nullptr, qkv_bf, nullptr, nullptr, 4096, 3072, 1024, 24, 8);
    attn_mfma<true><<<dim3(16, 16, 2), 256, 0, stream>>>(qkv_bf, 3072, qkv_bf, 3072, 1024, 2048, y_bf, 2048);
    gemm_bt<2><<<256, 256, 0, stream>>>(y_bf, wosa_t, x1, nullptr, b_out_sa, x, 4096, 1024, 1024, 8, 8);

    // --- cross-attention block ---
    ln_bf16<<<4096, 256, 0, stream>>>(x1, g2, bb2, h_bf);
    gemm_bt<0><<<256, 256, 0, stream>>>(h_bf, wq_t, nullptr, qca_bf, nullptr, nullptr, 4096, 1024, 1024, 8, 8);
    cvt_f32_bf16<<<4096, 256, 0, stream>>>(ctx, hc_bf, 1048576);
    gemm_bt<0><<<512, 256, 0, stream>>>(hc_bf, wkv_t, nullptr, kv_bf, nullptr, nullptr, 4096, 2048, 1024, 16, 8);
    attn_mfma<false><<<dim3(16, 16, 2), 256, 0, stream>>>(qca_bf, 1024, kv_bf, 2048, 0, 1024, y_bf, 2048);
    gemm_bt<2><<<256, 256, 0, stream>>>(y_bf, woca_t, x2, nullptr, b_out_ca, x1, 4096, 1024, 1024, 8, 8);

    // --- MLP block ---
    ln_bf16<<<4096, 256, 0, stream>>>(x2, g3, bb3, h_bf);
    gemm_bt<1><<<1024, 256, 0, stream>>>(h_bf, w1_t, nullptr, m1_bf, b1, nullptr, 4096, 4096, 1024, 32, 8);
    gemm_bt<2><<<256, 256, 0, stream>>>(m1_bf, w2_t, (float*)d_out, nullptr, b2, x2, 4096, 1024, 4096, 8, 2);
}

// Round 11
// 475.397 us; speedup vs baseline: 1.0023x; 1.0023x over previous
//
#include <hip/hip_runtime.h>
#include <hip/hip_bf16.h>

#define D_   1024
#define NH_  16
#define DH_  64
#define T_   2048
#define S_   2048
#define B_   2
#define FF_  4096

typedef __bf16 bf16x8 __attribute__((ext_vector_type(8)));
typedef float  f32x4  __attribute__((ext_vector_type(4)));
typedef unsigned int u32x4 __attribute__((ext_vector_type(4)));

static __device__ __forceinline__ unsigned short f2bf(float f) {
    union { float f; unsigned int i; } v; v.f = f;
    unsigned int x = v.i;
    return (unsigned short)((x + 0x7fffu + ((x >> 16) & 1u)) >> 16);
}
static __device__ __forceinline__ float fexp2(float x) {
    return __builtin_amdgcn_exp2f(x);          // raw v_exp_f32 (fast, 1 VALU op)
}

// async global->LDS, 16B per lane; LDS dest is wave-uniform base + lane*16
static __device__ __forceinline__ void gld16(const unsigned short* g, unsigned short* l) {
    __builtin_amdgcn_global_load_lds(
        (const __attribute__((address_space(1))) void*)g,
        (__attribute__((address_space(3))) void*)l, 16, 0, 0);
}

// ---------------- weight transpose: W[K][N] f32 -> Wt[N][K] bf16 ----------------
__global__ __launch_bounds__(256) void transpose_w(const float* __restrict__ W,
                                                   unsigned short* __restrict__ Wt,
                                                   int K, int N) {
    __shared__ float tile[32][33];
    int n0 = blockIdx.x * 32, k0 = blockIdx.y * 32;
    int c = threadIdx.x & 31, r0 = threadIdx.x >> 5;
    #pragma unroll
    for (int i = 0; i < 4; ++i) {
        int r = r0 + i * 8;
        tile[r][c] = W[(size_t)(k0 + r) * N + n0 + c];
    }
    __syncthreads();
    #pragma unroll
    for (int i = 0; i < 4; ++i) {
        int r = r0 + i * 8;
        Wt[(size_t)(n0 + r) * K + k0 + c] = f2bf(tile[c][r]);
    }
}

// ---------------- LayerNorm (row of 1024 f32) -> bf16 ----------------
__global__ __launch_bounds__(256) void ln_bf16(const float* __restrict__ x,
                                               const float* __restrict__ g,
                                               const float* __restrict__ b,
                                               unsigned short* __restrict__ out) {
    int row = blockIdx.x;
    int t = threadIdx.x;
    const float4* xr = (const float4*)(x + (size_t)row * D_);
    float4 v = xr[t];
    float s = v.x + v.y + v.z + v.w;
    float s2 = v.x*v.x + v.y*v.y + v.z*v.z + v.w*v.w;
    #pragma unroll
    for (int o = 32; o > 0; o >>= 1) { s += __shfl_down(s, o); s2 += __shfl_down(s2, o); }
    __shared__ float red[8];
    int wid = t >> 6, lane = t & 63;
    if (lane == 0) { red[wid*2] = s; red[wid*2+1] = s2; }
    __syncthreads();
    float ts  = red[0] + red[2] + red[4] + red[6];
    float ts2 = red[1] + red[3] + red[5] + red[7];
    float mu = ts * (1.0f / D_);
    float var = ts2 * (1.0f / D_) - mu * mu;
    float rstd = rsqrtf(var + 1e-5f);
    float4 gv = ((const float4*)g)[t];
    float4 bv = ((const float4*)b)[t];
    ushort4 o4;
    o4.x = f2bf((v.x - mu) * rstd * gv.x + bv.x);
    o4.y = f2bf((v.y - mu) * rstd * gv.y + bv.y);
    o4.z = f2bf((v.z - mu) * rstd * gv.z + bv.z);
    o4.w = f2bf((v.w - mu) * rstd * gv.w + bv.w);
    ((ushort4*)(out + (size_t)row * D_))[t] = o4;
}

// ---------------- f32 -> bf16 convert ----------------
__global__ __launch_bounds__(256) void cvt_f32_bf16(const float* __restrict__ in,
                                                    unsigned short* __restrict__ out, int n4) {
    int i = blockIdx.x * 256 + threadIdx.x;
    if (i < n4) {
        float4 v = ((const float4*)in)[i];
        ushort4 o; o.x = f2bf(v.x); o.y = f2bf(v.y); o.z = f2bf(v.z); o.w = f2bf(v.w);
        ((ushort4*)out)[i] = o;
    }
}

// ---------------- GEMM: C[M][N] = A[M][K](bf16) @ Bt[N][K]^T (bf16) ----------------
// m97 structure + L2 rasterization (unchanged — verified round 5/6).
template<int EPI>
__global__ __launch_bounds__(256) void gemm_bt(const unsigned short* __restrict__ A,
                                               const unsigned short* __restrict__ Bt,
                                               float* __restrict__ Cf,
                                               unsigned short* __restrict__ Cb,
                                               const float* __restrict__ bias,
                                               const float* __restrict__ resid,
                                               int M, int N, int K, int gn, int nb) {
    __shared__ unsigned short As[128 * 32];
    __shared__ unsigned short Bs[128 * 32];
    int tid = threadIdx.x;
    int lane = tid & 63, wv = tid >> 6;
    int wm = wv >> 1, wn = wv & 1;
    int lr = lane & 15, lg = lane >> 4;

    int bid = blockIdx.x, nwg = gridDim.x;
    int q8 = nwg >> 3, r8 = nwg & 7;
    int xcd = bid & 7, idx = bid >> 3;
    int wg = (xcd < r8 ? xcd * (q8 + 1) : r8 * (q8 + 1) + (xcd - r8) * q8) + idx;
    int gm = nwg / gn;
    int bandsz = gm * nb;
    int band = wg / bandsz;
    int rem = wg - band * bandsz;
    int mt = rem / nb;
    int nt = band * nb + (rem - mt * nb);
    int m0 = mt * 128, n0 = nt * 128;

    int csw = ((lane & 3) ^ ((lane >> 3) & 3)) * 8;
    const unsigned short* aSrc[2];
    const unsigned short* bSrc[2];
    unsigned short* aDst[2];
    unsigned short* bDst[2];
    #pragma unroll
    for (int i = 0; i < 2; ++i) {
        int rblk = wv * 2 + i;
        int row = rblk * 16 + (lane >> 2);
        aSrc[i] = A  + (size_t)(m0 + row) * K + csw;
        bSrc[i] = Bt + (size_t)(n0 + row) * K + csw;
        aDst[i] = &As[rblk * 512];
        bDst[i] = &Bs[rblk * 512];
    }

    const f32x4 vzero = {0.f, 0.f, 0.f, 0.f};
    f32x4 acc[4][4];
    #pragma unroll
    for (int i = 0; i < 4; ++i)
        #pragma unroll
        for (int j = 0; j < 4; ++j) acc[i][j] = vzero;

    for (int k0 = 0; k0 < K; k0 += 32) {
        __syncthreads();
        #pragma unroll
        for (int i = 0; i < 2; ++i) {
            gld16(aSrc[i] + k0, aDst[i]);
            gld16(bSrc[i] + k0, bDst[i]);
        }
        __syncthreads();
        bf16x8 a[4], b[4];
        #pragma unroll
        for (int f = 0; f < 4; ++f) {
            int ra = wm * 64 + f * 16 + lr;
            a[f] = __builtin_bit_cast(bf16x8, *(const u32x4*)&As[ra * 32 + ((lg ^ ((ra >> 1) & 3)) << 3)]);
            int rb = wn * 64 + f * 16 + lr;
            b[f] = __builtin_bit_cast(bf16x8, *(const u32x4*)&Bs[rb * 32 + ((lg ^ ((rb >> 1) & 3)) << 3)]);
        }
        #pragma unroll
        for (int i = 0; i < 4; ++i)
            #pragma unroll
            for (int j = 0; j < 4; ++j)
                acc[i][j] = __builtin_amdgcn_mfma_f32_16x16x32_bf16(a[i], b[j], acc[i][j], 0, 0, 0);
    }

    #pragma unroll
    for (int i = 0; i < 4; ++i) {
        int rbase = m0 + wm * 64 + i * 16 + lg * 4;
        #pragma unroll
        for (int j = 0; j < 4; ++j) {
            int col = n0 + wn * 64 + j * 16 + lr;
            #pragma unroll
            for (int r = 0; r < 4; ++r) {
                int row = rbase + r;
                float v = acc[i][j][r];
                if (EPI == 0) {
                    Cb[(size_t)row * N + col] = f2bf(v);
                } else if (EPI == 1) {
                    v += bias[col];
                    v = v > 0.f ? v : 0.f;
                    Cb[(size_t)row * N + col] = f2bf(v);
                } else {
                    v += bias[col] + resid[(size_t)row * N + col];
                    Cf[(size_t)row * N + col] = v;
                }
            }
        }
    }
}

// ---------------- MFMA flash attention, 32 q-rows per wave (2 groups of 16) ----------------
// Round-6 verified structure (P via per-wave LDS, straight QK^T). Only change: fast exp2
// via __builtin_amdgcn_exp2f (raw v_exp_f32) instead of OCML exp2f.
// NOTE: launch_bounds MUST stay (256,2) — unified VGPR+AGPR need ~160/wave; higher
// min-waves caps regs below need and spills (round3 (256,6)=435us; round5 (256,4)=295us).
template<bool CAUSAL>
__global__ __launch_bounds__(256, 2) void attn_mfma(
    const unsigned short* __restrict__ Qsrc, int q_stride,
    const unsigned short* __restrict__ KVsrc, int kv_stride,
    int k_off0, int v_off0,
    unsigned short* __restrict__ Y, int Lk)
{
    __shared__ unsigned short Kl[64 * 64];        // [key][dh], chunk c=dh>>3 at c^(key&7)
    __shared__ unsigned short Vt[64 * 64];        // [dh][key], chunk c=key>>3 at c^(dh&7)
    __shared__ unsigned short Pl[4][2][16 * 64];  // per-wave, per-group [q][key], chunk c^(q&7)

    const float SCL = 0.125f * 1.44269504f;       // 1/sqrt(DH) * log2(e)

    const int tid = threadIdx.x;
    const int lane = tid & 63, w = tid >> 6;
    const int lr = lane & 15, lg = lane >> 4;
    const int h = blockIdx.y, b = blockIdx.z;
    const int bx = blockIdx.x;

    int qw[2];
    if (CAUSAL) {
        qw[0] = bx * 64 + w * 16;
        qw[1] = (2 * (int)gridDim.x - 1 - bx) * 64 + w * 16;
    } else {
        qw[0] = bx * 128 + w * 16;
        qw[1] = bx * 128 + 64 + w * 16;
    }
    const int ntiles = CAUSAL ? (2 * (int)gridDim.x - bx) : (Lk / 64);

    bf16x8 qf[2][2];
    #pragma unroll
    for (int g = 0; g < 2; ++g) {
        const unsigned short* qp = Qsrc + ((size_t)(b * T_) + qw[g] + lr) * q_stride + h * DH_ + lg * 8;
        qf[g][0] = __builtin_bit_cast(bf16x8, *(const u32x4*)qp);
        qf[g][1] = __builtin_bit_cast(bf16x8, *(const u32x4*)(qp + 32));
    }
    bf16x8 onesf;
    #pragma unroll
    for (int i = 0; i < 8; ++i) onesf[i] = (__bf16)1.0f;

    f32x4 o[2][4];
    f32x4 accl[2];
    float mrow[2][4];                 // running max in log2 domain
    #pragma unroll
    for (int g = 0; g < 2; ++g) {
        #pragma unroll
        for (int f = 0; f < 4; ++f) o[g][f] = {0.f, 0.f, 0.f, 0.f};
        accl[g] = {0.f, 0.f, 0.f, 0.f};
        #pragma unroll
        for (int r = 0; r < 4; ++r) mrow[g][r] = -3e38f;
    }

    // staging thread mappings (block-constant)
    const int kkey = tid >> 2, kdc = (tid & 3) * 2;   // K: 4 threads/key, 2x16B chunks each
    const unsigned short* kbase = KVsrc + ((size_t)(b * Lk) + kkey) * kv_stride + k_off0 + h * DH_ + kdc * 8;
    const int vkey = lane;                            // V: key per lane; wave w -> dh chunks {w, w+4}
    const unsigned short* vbase = KVsrc + ((size_t)(b * Lk) + vkey) * kv_stride + v_off0 + h * DH_;

    u32x4 kr0 = *(const u32x4*)kbase;
    u32x4 kr1 = *(const u32x4*)(kbase + 8);
    u32x4 vr0 = *(const u32x4*)(vbase + w * 8);
    u32x4 vr1 = *(const u32x4*)(vbase + (w + 4) * 8);

    for (int t = 0; t < ntiles; ++t) {
        const int k0 = t * 64;
        __syncthreads();
        // ---- write staged registers to LDS ----
        {
            int s0 = (kdc    ) ^ (kkey & 7);
            int s1 = (kdc + 1) ^ (kkey & 7);
            *(u32x4*)&Kl[kkey * 64 + s0 * 8] = kr0;
            *(u32x4*)&Kl[kkey * 64 + s1 * 8] = kr1;
        }
        {
            const unsigned short* u0 = (const unsigned short*)&vr0;
            const unsigned short* u1 = (const unsigned short*)&vr1;
            int khi = vkey >> 3, klo = vkey & 7;
            #pragma unroll
            for (int j = 0; j < 8; ++j) {
                Vt[(w * 8 + j)       * 64 + ((khi ^ j) << 3) + klo] = u0[j];
                Vt[((w + 4) * 8 + j) * 64 + ((khi ^ j) << 3) + klo] = u1[j];
            }
        }
        __syncthreads();
        // ---- prefetch next tile into registers ----
        if (t + 1 < ntiles) {
            const unsigned short* kp = kbase + (size_t)(k0 + 64) * kv_stride;
            kr0 = *(const u32x4*)kp;
            kr1 = *(const u32x4*)(kp + 8);
            const unsigned short* vp = vbase + (size_t)(k0 + 64) * kv_stride;
            vr0 = *(const u32x4*)(vp + w * 8);
            vr1 = *(const u32x4*)(vp + (w + 4) * 8);
        }
        const bool act0 = !CAUSAL || (t <= bx);   // group1 always active

        // ---- QK^T for both groups, sharing each K-fragment read ----
        f32x4 s[2][4];
        #pragma unroll
        for (int g = 0; g < 2; ++g)
            #pragma unroll
            for (int f = 0; f < 4; ++f) s[g][f] = {0.f, 0.f, 0.f, 0.f};
        __builtin_amdgcn_s_setprio(1);
        #pragma unroll
        for (int ck = 0; ck < 2; ++ck) {
            int kc = lg + 4 * ck;
            #pragma unroll
            for (int f = 0; f < 4; ++f) {
                int key = f * 16 + lr;
                bf16x8 kb = __builtin_bit_cast(bf16x8,
                    *(const u32x4*)&Kl[key * 64 + ((kc ^ (key & 7)) << 3)]);
                if (act0) s[0][f] = __builtin_amdgcn_mfma_f32_16x16x32_bf16(qf[0][ck], kb, s[0][f], 0, 0, 0);
                s[1][f] = __builtin_amdgcn_mfma_f32_16x16x32_bf16(qf[1][ck], kb, s[1][f], 0, 0, 0);
            }
        }
        __builtin_amdgcn_s_setprio(0);

        // ---- per-group: mask, online softmax (log2 domain, defer-max), P pack+store ----
        #pragma unroll
        for (int g = 0; g < 2; ++g) {
            if (g == 0 && !act0) continue;
            if (CAUSAL && (k0 + 63 > qw[g])) {
                int dq = qw[g] + lg * 4 - k0 - lr;   // mask if f*16 - r > dq
                #pragma unroll
                for (int f = 0; f < 4; ++f)
                    #pragma unroll
                    for (int r = 0; r < 4; ++r)
                        s[g][f][r] = (f * 16 - r > dq) ? -3e38f : s[g][f][r];
            }
            float mx2[4];
            #pragma unroll
            for (int r = 0; r < 4; ++r) {
                float mx = fmaxf(fmaxf(s[g][0][r], s[g][1][r]), fmaxf(s[g][2][r], s[g][3][r]));
                mx = fmaxf(mx, __shfl_xor(mx, 1));
                mx = fmaxf(mx, __shfl_xor(mx, 2));
                mx = fmaxf(mx, __shfl_xor(mx, 4));
                mx = fmaxf(mx, __shfl_xor(mx, 8));
                mx2[r] = mx * SCL;
            }
            bool need = false;
            #pragma unroll
            for (int r = 0; r < 4; ++r) need = need || (mx2[r] > mrow[g][r] + 8.0f);
            if (__any(need ? 1 : 0)) {
                float corr[4];
                #pragma unroll
                for (int r = 0; r < 4; ++r) {
                    float mn = fmaxf(mrow[g][r], mx2[r]);
                    corr[r] = fexp2(mrow[g][r] - mn);
                    mrow[g][r] = mn;
                }
                #pragma unroll
                for (int f = 0; f < 4; ++f)
                    #pragma unroll
                    for (int r = 0; r < 4; ++r) o[g][f][r] *= corr[r];
                #pragma unroll
                for (int r = 0; r < 4; ++r) accl[g][r] *= corr[r];
            }
            unsigned short* pw = &Pl[w][g][0];
            #pragma unroll
            for (int f = 0; f < 4; ++f) {
                int key = f * 16 + lr;
                int khi2 = key >> 3, klo2 = key & 7;
                #pragma unroll
                for (int r = 0; r < 4; ++r) {
                    float p = fexp2(s[g][f][r] * SCL - mrow[g][r]);
                    union { float f; unsigned int i; } cv; cv.f = p;
                    int q = lg * 4 + r;
                    pw[q * 64 + ((khi2 ^ (q & 7)) << 3) + klo2] =
                        (unsigned short)((cv.i + 0x8000u) >> 16);
                }
            }
        }

        // ---- PV + row-sum, sharing each V-fragment read across groups ----
        __builtin_amdgcn_s_setprio(1);
        #pragma unroll
        for (int ck = 0; ck < 2; ++ck) {
            int kc = lg + 4 * ck;
            bf16x8 pa0, pa1;
            if (act0) {
                pa0 = __builtin_bit_cast(bf16x8,
                    *(const u32x4*)&Pl[w][0][lr * 64 + ((kc ^ (lr & 7)) << 3)]);
                accl[0] = __builtin_amdgcn_mfma_f32_16x16x32_bf16(pa0, onesf, accl[0], 0, 0, 0);
            }
            pa1 = __builtin_bit_cast(bf16x8,
                *(const u32x4*)&Pl[w][1][lr * 64 + ((kc ^ (lr & 7)) << 3)]);
            accl[1] = __builtin_amdgcn_mfma_f32_16x16x32_bf16(pa1, onesf, accl[1], 0, 0, 0);
            #pragma unroll
            for (int f = 0; f < 4; ++f) {
                int dh = f * 16 + lr;
                bf16x8 vb = __builtin_bit_cast(bf16x8,
                    *(const u32x4*)&Vt[dh * 64 + ((kc ^ (dh & 7)) << 3)]);
                if (act0) o[0][f] = __builtin_amdgcn_mfma_f32_16x16x32_bf16(pa0, vb, o[0][f], 0, 0, 0);
                o[1][f] = __builtin_amdgcn_mfma_f32_16x16x32_bf16(pa1, vb, o[1][f], 0, 0, 0);
            }
        }
        __builtin_amdgcn_s_setprio(0);
    }

    // ---- epilogue (both groups) ----
    #pragma unroll
    for (int g = 0; g < 2; ++g) {
        float inv[4];
        #pragma unroll
        for (int r = 0; r < 4; ++r) inv[r] = 1.f / accl[g][r];
        #pragma unroll
        for (int f = 0; f < 4; ++f)
            #pragma unroll
            for (int r = 0; r < 4; ++r) {
                float v = o[g][f][r] * inv[r];
                Y[((size_t)(b * T_) + qw[g] + lg * 4 + r) * D_ + h * DH_ + f * 16 + lr] = f2bf(v);
            }
    }
}

extern "C" void kernel_launch(void* const* d_in, const int* in_sizes, int n_in,
                              void* d_out, int out_size, void* d_ws, size_t ws_size,
                              hipStream_t stream) {
    const float* x        = (const float*)d_in[0];
    const float* ctx      = (const float*)d_in[1];
    const float* W_qkv    = (const float*)d_in[2];
    const float* W_out_sa = (const float*)d_in[3];
    const float* b_out_sa = (const float*)d_in[4];
    const float* W_q      = (const float*)d_in[5];
    const float* W_kv     = (const float*)d_in[6];
    const float* W_out_ca = (const float*)d_in[7];
    const float* b_out_ca = (const float*)d_in[8];
    const float* W1       = (const float*)d_in[9];
    const float* b1       = (const float*)d_in[10];
    const float* W2       = (const float*)d_in[11];
    const float* b2       = (const float*)d_in[12];
    const float* g1  = (const float*)d_in[13];
    const float* bb1 = (const float*)d_in[14];
    const float* g2  = (const float*)d_in[15];
    const float* bb2 = (const float*)d_in[16];
    const float* g3  = (const float*)d_in[17];
    const float* bb3 = (const float*)d_in[18];

    char* ws = (char*)d_ws;
    size_t off = 0;
    auto alloc = [&](size_t bytes) { char* p = ws + off; off += (bytes + 255) & ~(size_t)255; return p; };

    unsigned short* wqkv_t = (unsigned short*)alloc(3072UL * 1024 * 2);
    unsigned short* wosa_t = (unsigned short*)alloc(1024UL * 1024 * 2);
    unsigned short* wq_t   = (unsigned short*)alloc(1024UL * 1024 * 2);
    unsigned short* wkv_t  = (unsigned short*)alloc(2048UL * 1024 * 2);
    unsigned short* woca_t = (unsigned short*)alloc(1024UL * 1024 * 2);
    unsigned short* w1_t   = (unsigned short*)alloc(4096UL * 1024 * 2);
    unsigned short* w2_t   = (unsigned short*)alloc(1024UL * 4096 * 2);
    unsigned short* h_bf   = (unsigned short*)alloc(4096UL * 1024 * 2);
    float*          x1     = (float*)alloc(4096UL * 1024 * 4);
    unsigned short* y_bf   = (unsigned short*)alloc(4096UL * 1024 * 2);
    unsigned short* qkv_bf = (unsigned short*)alloc(4096UL * 3072 * 2);
    unsigned short* qca_bf = (unsigned short*)alloc(4096UL * 1024 * 2);
    unsigned short* kv_bf  = (unsigned short*)alloc(4096UL * 2048 * 2);
    unsigned short* hc_bf  = (unsigned short*)alloc(4096UL * 1024 * 2);
    unsigned short* m1_bf  = qkv_bf;   // reuse: qkv+qca regions dead by MLP
    float* x2 = (float*)d_out;

    // weight transposes (f32 KxN -> bf16 NxK)
    transpose_w<<<dim3(3072/32, 1024/32), 256, 0, stream>>>(W_qkv,    wqkv_t, 1024, 3072);
    transpose_w<<<dim3(1024/32, 1024/32), 256, 0, stream>>>(W_out_sa, wosa_t, 1024, 1024);
    transpose_w<<<dim3(1024/32, 1024/32), 256, 0, stream>>>(W_q,      wq_t,   1024, 1024);
    transpose_w<<<dim3(2048/32, 1024/32), 256, 0, stream>>>(W_kv,     wkv_t,  1024, 2048);
    transpose_w<<<dim3(1024/32, 1024/32), 256, 0, stream>>>(W_out_ca, woca_t, 1024, 1024);
    transpose_w<<<dim3(4096/32, 1024/32), 256, 0, stream>>>(W1,       w1_t,   1024, 4096);
    transpose_w<<<dim3(1024/32, 4096/32), 256, 0, stream>>>(W2,       w2_t,   4096, 1024);

    // --- self-attention block ---
    ln_bf16<<<4096, 256, 0, stream>>>(x, g1, bb1, h_bf);
    gemm_bt<0><<<768, 256, 0, stream>>>(h_bf, wqkv_t, nullptr, qkv_bf, nullptr, nullptr, 4096, 3072, 1024, 24, 8);
    attn_mfma<true><<<dim3(16, 16, 2), 256, 0, stream>>>(qkv_bf, 3072, qkv_bf, 3072, 1024, 2048, y_bf, 2048);
    gemm_bt<2><<<256, 256, 0, stream>>>(y_bf, wosa_t, x1, nullptr, b_out_sa, x, 4096, 1024, 1024, 8, 8);

    // --- cross-attention block ---
    ln_bf16<<<4096, 256, 0, stream>>>(x1, g2, bb2, h_bf);
    gemm_bt<0><<<256, 256, 0, stream>>>(h_bf, wq_t, nullptr, qca_bf, nullptr, nullptr, 4096, 1024, 1024, 8, 8);
    cvt_f32_bf16<<<4096, 256, 0, stream>>>(ctx, hc_bf, 1048576);
    gemm_bt<0><<<512, 256, 0, stream>>>(hc_bf, wkv_t, nullptr, kv_bf, nullptr, nullptr, 4096, 2048, 1024, 16, 8);
    attn_mfma<false><<<dim3(16, 16, 2), 256, 0, stream>>>(qca_bf, 1024, kv_bf, 2048, 0, 1024, y_bf, 2048);
    gemm_bt<2><<<256, 256, 0, stream>>>(y_bf, woca_t, x2, nullptr, b_out_ca, x1, 4096, 1024, 1024, 8, 8);

    // --- MLP block ---
    ln_bf16<<<4096, 256, 0, stream>>>(x2, g3, bb3, h_bf);
    gemm_bt<1><<<1024, 256, 0, stream>>>(h_bf, w1_t, nullptr, m1_bf, b1, nullptr, 4096, 4096, 1024, 32, 8);
    gemm_bt<2><<<256, 256, 0, stream>>>(m1_bf, w2_t, (float*)d_out, nullptr, b2, x2, 4096, 1024, 4096, 8, 2);
}

// Round 12
// 453.600 us; speedup vs baseline: 1.0504x; 1.0481x over previous
//
#include <hip/hip_runtime.h>
#include <hip/hip_bf16.h>

#define D_   1024
#define NH_  16
#define DH_  64
#define T_   2048
#define S_   2048
#define B_   2
#define FF_  4096

typedef __bf16 bf16x8 __attribute__((ext_vector_type(8)));
typedef float  f32x4  __attribute__((ext_vector_type(4)));
typedef unsigned int u32x4 __attribute__((ext_vector_type(4)));

static __device__ __forceinline__ unsigned short f2bf(float f) {
    union { float f; unsigned int i; } v; v.f = f;
    unsigned int x = v.i;
    return (unsigned short)((x + 0x7fffu + ((x >> 16) & 1u)) >> 16);
}
static __device__ __forceinline__ float fexp2(float x) {
    return __builtin_amdgcn_exp2f(x);          // raw v_exp_f32 (fast, 1 VALU op)
}

// async global->LDS, 16B per lane; LDS dest is wave-uniform base + lane*16
static __device__ __forceinline__ void gld16(const unsigned short* g, unsigned short* l) {
    __builtin_amdgcn_global_load_lds(
        (const __attribute__((address_space(1))) void*)g,
        (__attribute__((address_space(3))) void*)l, 16, 0, 0);
}

// ---------------- weight transpose: W[K][N] f32 -> Wt[N][K] bf16 ----------------
__global__ __launch_bounds__(256) void transpose_w(const float* __restrict__ W,
                                                   unsigned short* __restrict__ Wt,
                                                   int K, int N) {
    __shared__ float tile[32][33];
    int n0 = blockIdx.x * 32, k0 = blockIdx.y * 32;
    int c = threadIdx.x & 31, r0 = threadIdx.x >> 5;
    #pragma unroll
    for (int i = 0; i < 4; ++i) {
        int r = r0 + i * 8;
        tile[r][c] = W[(size_t)(k0 + r) * N + n0 + c];
    }
    __syncthreads();
    #pragma unroll
    for (int i = 0; i < 4; ++i) {
        int r = r0 + i * 8;
        Wt[(size_t)(n0 + r) * K + k0 + c] = f2bf(tile[c][r]);
    }
}

// ---------------- LayerNorm (row of 1024 f32) -> bf16 ----------------
__global__ __launch_bounds__(256) void ln_bf16(const float* __restrict__ x,
                                               const float* __restrict__ g,
                                               const float* __restrict__ b,
                                               unsigned short* __restrict__ out) {
    int row = blockIdx.x;
    int t = threadIdx.x;
    const float4* xr = (const float4*)(x + (size_t)row * D_);
    float4 v = xr[t];
    float s = v.x + v.y + v.z + v.w;
    float s2 = v.x*v.x + v.y*v.y + v.z*v.z + v.w*v.w;
    #pragma unroll
    for (int o = 32; o > 0; o >>= 1) { s += __shfl_down(s, o); s2 += __shfl_down(s2, o); }
    __shared__ float red[8];
    int wid = t >> 6, lane = t & 63;
    if (lane == 0) { red[wid*2] = s; red[wid*2+1] = s2; }
    __syncthreads();
    float ts  = red[0] + red[2] + red[4] + red[6];
    float ts2 = red[1] + red[3] + red[5] + red[7];
    float mu = ts * (1.0f / D_);
    float var = ts2 * (1.0f / D_) - mu * mu;
    float rstd = rsqrtf(var + 1e-5f);
    float4 gv = ((const float4*)g)[t];
    float4 bv = ((const float4*)b)[t];
    ushort4 o4;
    o4.x = f2bf((v.x - mu) * rstd * gv.x + bv.x);
    o4.y = f2bf((v.y - mu) * rstd * gv.y + bv.y);
    o4.z = f2bf((v.z - mu) * rstd * gv.z + bv.z);
    o4.w = f2bf((v.w - mu) * rstd * gv.w + bv.w);
    ((ushort4*)(out + (size_t)row * D_))[t] = o4;
}

// ---------------- f32 -> bf16 convert ----------------
__global__ __launch_bounds__(256) void cvt_f32_bf16(const float* __restrict__ in,
                                                    unsigned short* __restrict__ out, int n4) {
    int i = blockIdx.x * 256 + threadIdx.x;
    if (i < n4) {
        float4 v = ((const float4*)in)[i];
        ushort4 o; o.x = f2bf(v.x); o.y = f2bf(v.y); o.z = f2bf(v.z); o.w = f2bf(v.w);
        ((ushort4*)out)[i] = o;
    }
}

// ---------------- GEMM: C[M][N] = A[M][K](bf16) @ Bt[N][K]^T (bf16) ----------------
// L2 rasterization (round 5) + T3 minimum-2-phase double-buffer (this round):
// STAGE(buf^1, t+1) issued BEFORE ds_read+MFMA of buf[cur]; single vmcnt(0)+s_barrier
// per K-step AFTER compute, so prefetch latency hides under compute instead of the
// m97 barrier-drain. Safety: all ds_reads consumed by MFMA (compiler lgkmcnt) before
// the barrier; gld16 writes target the opposite buffer and drain at vmcnt(0).
// EPI 0: bf16 out, no bias | 1: bf16 out, +bias, relu | 2: f32 out, +bias, +residual
template<int EPI>
__global__ __launch_bounds__(256) void gemm_bt(const unsigned short* __restrict__ A,
                                               const unsigned short* __restrict__ Bt,
                                               float* __restrict__ Cf,
                                               unsigned short* __restrict__ Cb,
                                               const float* __restrict__ bias,
                                               const float* __restrict__ resid,
                                               int M, int N, int K, int gn, int nb) {
    __shared__ unsigned short As[2][128 * 32];
    __shared__ unsigned short Bs[2][128 * 32];
    int tid = threadIdx.x;
    int lane = tid & 63, wv = tid >> 6;
    int wm = wv >> 1, wn = wv & 1;
    int lr = lane & 15, lg = lane >> 4;

    int bid = blockIdx.x, nwg = gridDim.x;
    int q8 = nwg >> 3, r8 = nwg & 7;
    int xcd = bid & 7, idx = bid >> 3;
    int wg = (xcd < r8 ? xcd * (q8 + 1) : r8 * (q8 + 1) + (xcd - r8) * q8) + idx;
    int gm = nwg / gn;
    int bandsz = gm * nb;
    int band = wg / bandsz;
    int rem = wg - band * bandsz;
    int mt = rem / nb;
    int nt = band * nb + (rem - mt * nb);
    int m0 = mt * 128, n0 = nt * 128;

    int csw = ((lane & 3) ^ ((lane >> 3) & 3)) * 8;
    const unsigned short* aSrc[2];
    const unsigned short* bSrc[2];
    int dOff[2];
    #pragma unroll
    for (int i = 0; i < 2; ++i) {
        int rblk = wv * 2 + i;
        int row = rblk * 16 + (lane >> 2);
        aSrc[i] = A  + (size_t)(m0 + row) * K + csw;
        bSrc[i] = Bt + (size_t)(n0 + row) * K + csw;
        dOff[i] = rblk * 512;
    }

    const f32x4 vzero = {0.f, 0.f, 0.f, 0.f};
    f32x4 acc[4][4];
    #pragma unroll
    for (int i = 0; i < 4; ++i)
        #pragma unroll
        for (int j = 0; j < 4; ++j) acc[i][j] = vzero;

    const int nsteps = K >> 5;   // K/32

    // prologue: stage K-step 0 into buffer 0
    #pragma unroll
    for (int i = 0; i < 2; ++i) {
        gld16(aSrc[i], &As[0][dOff[i]]);
        gld16(bSrc[i], &Bs[0][dOff[i]]);
    }
    asm volatile("s_waitcnt vmcnt(0)" ::: "memory");
    __builtin_amdgcn_s_barrier();

    int cur = 0;
    for (int t = 0; t < nsteps; ++t) {
        // issue next-tile prefetch into the other buffer (overlaps this tile's compute)
        if (t + 1 < nsteps) {
            int k0n = (t + 1) << 5;
            #pragma unroll
            for (int i = 0; i < 2; ++i) {
                gld16(aSrc[i] + k0n, &As[cur ^ 1][dOff[i]]);
                gld16(bSrc[i] + k0n, &Bs[cur ^ 1][dOff[i]]);
            }
        }
        // compute current buffer
        bf16x8 a[4], b[4];
        #pragma unroll
        for (int f = 0; f < 4; ++f) {
            int ra = wm * 64 + f * 16 + lr;
            a[f] = __builtin_bit_cast(bf16x8, *(const u32x4*)&As[cur][ra * 32 + ((lg ^ ((ra >> 1) & 3)) << 3)]);
            int rb = wn * 64 + f * 16 + lr;
            b[f] = __builtin_bit_cast(bf16x8, *(const u32x4*)&Bs[cur][rb * 32 + ((lg ^ ((rb >> 1) & 3)) << 3)]);
        }
        __builtin_amdgcn_s_setprio(1);
        #pragma unroll
        for (int i = 0; i < 4; ++i)
            #pragma unroll
            for (int j = 0; j < 4; ++j)
                acc[i][j] = __builtin_amdgcn_mfma_f32_16x16x32_bf16(a[i], b[j], acc[i][j], 0, 0, 0);
        __builtin_amdgcn_s_setprio(0);
        // drain prefetch, then release buffers for next step
        asm volatile("s_waitcnt vmcnt(0)" ::: "memory");
        __builtin_amdgcn_s_barrier();
        cur ^= 1;
    }

    #pragma unroll
    for (int i = 0; i < 4; ++i) {
        int rbase = m0 + wm * 64 + i * 16 + lg * 4;
        #pragma unroll
        for (int j = 0; j < 4; ++j) {
            int col = n0 + wn * 64 + j * 16 + lr;
            #pragma unroll
            for (int r = 0; r < 4; ++r) {
                int row = rbase + r;
                float v = acc[i][j][r];
                if (EPI == 0) {
                    Cb[(size_t)row * N + col] = f2bf(v);
                } else if (EPI == 1) {
                    v += bias[col];
                    v = v > 0.f ? v : 0.f;
                    Cb[(size_t)row * N + col] = f2bf(v);
                } else {
                    v += bias[col] + resid[(size_t)row * N + col];
                    Cf[(size_t)row * N + col] = v;
                }
            }
        }
    }
}

// ---------------- MFMA flash attention, 32 q-rows per wave (2 groups of 16) ----------------
// Round-11 verified structure, UNCHANGED.
// NOTE: launch_bounds MUST stay (256,2) — unified VGPR+AGPR need ~160/wave; higher
// min-waves caps regs below need and spills (round3 (256,6)=435us; round5 (256,4)=295us).
template<bool CAUSAL>
__global__ __launch_bounds__(256, 2) void attn_mfma(
    const unsigned short* __restrict__ Qsrc, int q_stride,
    const unsigned short* __restrict__ KVsrc, int kv_stride,
    int k_off0, int v_off0,
    unsigned short* __restrict__ Y, int Lk)
{
    __shared__ unsigned short Kl[64 * 64];        // [key][dh], chunk c=dh>>3 at c^(key&7)
    __shared__ unsigned short Vt[64 * 64];        // [dh][key], chunk c=key>>3 at c^(dh&7)
    __shared__ unsigned short Pl[4][2][16 * 64];  // per-wave, per-group [q][key], chunk c^(q&7)

    const float SCL = 0.125f * 1.44269504f;       // 1/sqrt(DH) * log2(e)

    const int tid = threadIdx.x;
    const int lane = tid & 63, w = tid >> 6;
    const int lr = lane & 15, lg = lane >> 4;
    const int h = blockIdx.y, b = blockIdx.z;
    const int bx = blockIdx.x;

    int qw[2];
    if (CAUSAL) {
        qw[0] = bx * 64 + w * 16;
        qw[1] = (2 * (int)gridDim.x - 1 - bx) * 64 + w * 16;
    } else {
        qw[0] = bx * 128 + w * 16;
        qw[1] = bx * 128 + 64 + w * 16;
    }
    const int ntiles = CAUSAL ? (2 * (int)gridDim.x - bx) : (Lk / 64);

    bf16x8 qf[2][2];
    #pragma unroll
    for (int g = 0; g < 2; ++g) {
        const unsigned short* qp = Qsrc + ((size_t)(b * T_) + qw[g] + lr) * q_stride + h * DH_ + lg * 8;
        qf[g][0] = __builtin_bit_cast(bf16x8, *(const u32x4*)qp);
        qf[g][1] = __builtin_bit_cast(bf16x8, *(const u32x4*)(qp + 32));
    }
    bf16x8 onesf;
    #pragma unroll
    for (int i = 0; i < 8; ++i) onesf[i] = (__bf16)1.0f;

    f32x4 o[2][4];
    f32x4 accl[2];
    float mrow[2][4];                 // running max in log2 domain
    #pragma unroll
    for (int g = 0; g < 2; ++g) {
        #pragma unroll
        for (int f = 0; f < 4; ++f) o[g][f] = {0.f, 0.f, 0.f, 0.f};
        accl[g] = {0.f, 0.f, 0.f, 0.f};
        #pragma unroll
        for (int r = 0; r < 4; ++r) mrow[g][r] = -3e38f;
    }

    // staging thread mappings (block-constant)
    const int kkey = tid >> 2, kdc = (tid & 3) * 2;   // K: 4 threads/key, 2x16B chunks each
    const unsigned short* kbase = KVsrc + ((size_t)(b * Lk) + kkey) * kv_stride + k_off0 + h * DH_ + kdc * 8;
    const int vkey = lane;                            // V: key per lane; wave w -> dh chunks {w, w+4}
    const unsigned short* vbase = KVsrc + ((size_t)(b * Lk) + vkey) * kv_stride + v_off0 + h * DH_;

    u32x4 kr0 = *(const u32x4*)kbase;
    u32x4 kr1 = *(const u32x4*)(kbase + 8);
    u32x4 vr0 = *(const u32x4*)(vbase + w * 8);
    u32x4 vr1 = *(const u32x4*)(vbase + (w + 4) * 8);

    for (int t = 0; t < ntiles; ++t) {
        const int k0 = t * 64;
        __syncthreads();
        // ---- write staged registers to LDS ----
        {
            int s0 = (kdc    ) ^ (kkey & 7);
            int s1 = (kdc + 1) ^ (kkey & 7);
            *(u32x4*)&Kl[kkey * 64 + s0 * 8] = kr0;
            *(u32x4*)&Kl[kkey * 64 + s1 * 8] = kr1;
        }
        {
            const unsigned short* u0 = (const unsigned short*)&vr0;
            const unsigned short* u1 = (const unsigned short*)&vr1;
            int khi = vkey >> 3, klo = vkey & 7;
            #pragma unroll
            for (int j = 0; j < 8; ++j) {
                Vt[(w * 8 + j)       * 64 + ((khi ^ j) << 3) + klo] = u0[j];
                Vt[((w + 4) * 8 + j) * 64 + ((khi ^ j) << 3) + klo] = u1[j];
            }
        }
        __syncthreads();
        // ---- prefetch next tile into registers ----
        if (t + 1 < ntiles) {
            const unsigned short* kp = kbase + (size_t)(k0 + 64) * kv_stride;
            kr0 = *(const u32x4*)kp;
            kr1 = *(const u32x4*)(kp + 8);
            const unsigned short* vp = vbase + (size_t)(k0 + 64) * kv_stride;
            vr0 = *(const u32x4*)(vp + w * 8);
            vr1 = *(const u32x4*)(vp + (w + 4) * 8);
        }
        const bool act0 = !CAUSAL || (t <= bx);   // group1 always active

        // ---- QK^T for both groups, sharing each K-fragment read ----
        f32x4 s[2][4];
        #pragma unroll
        for (int g = 0; g < 2; ++g)
            #pragma unroll
            for (int f = 0; f < 4; ++f) s[g][f] = {0.f, 0.f, 0.f, 0.f};
        __builtin_amdgcn_s_setprio(1);
        #pragma unroll
        for (int ck = 0; ck < 2; ++ck) {
            int kc = lg + 4 * ck;
            #pragma unroll
            for (int f = 0; f < 4; ++f) {
                int key = f * 16 + lr;
                bf16x8 kb = __builtin_bit_cast(bf16x8,
                    *(const u32x4*)&Kl[key * 64 + ((kc ^ (key & 7)) << 3)]);
                if (act0) s[0][f] = __builtin_amdgcn_mfma_f32_16x16x32_bf16(qf[0][ck], kb, s[0][f], 0, 0, 0);
                s[1][f] = __builtin_amdgcn_mfma_f32_16x16x32_bf16(qf[1][ck], kb, s[1][f], 0, 0, 0);
            }
        }
        __builtin_amdgcn_s_setprio(0);

        // ---- per-group: mask, online softmax (log2 domain, defer-max), P pack+store ----
        #pragma unroll
        for (int g = 0; g < 2; ++g) {
            if (g == 0 && !act0) continue;
            if (CAUSAL && (k0 + 63 > qw[g])) {
                int dq = qw[g] + lg * 4 - k0 - lr;   // mask if f*16 - r > dq
                #pragma unroll
                for (int f = 0; f < 4; ++f)
                    #pragma unroll
                    for (int r = 0; r < 4; ++r)
                        s[g][f][r] = (f * 16 - r > dq) ? -3e38f : s[g][f][r];
            }
            float mx2[4];
            #pragma unroll
            for (int r = 0; r < 4; ++r) {
                float mx = fmaxf(fmaxf(s[g][0][r], s[g][1][r]), fmaxf(s[g][2][r], s[g][3][r]));
                mx = fmaxf(mx, __shfl_xor(mx, 1));
                mx = fmaxf(mx, __shfl_xor(mx, 2));
                mx = fmaxf(mx, __shfl_xor(mx, 4));
                mx = fmaxf(mx, __shfl_xor(mx, 8));
                mx2[r] = mx * SCL;
            }
            bool need = false;
            #pragma unroll
            for (int r = 0; r < 4; ++r) need = need || (mx2[r] > mrow[g][r] + 8.0f);
            if (__any(need ? 1 : 0)) {
                float corr[4];
                #pragma unroll
                for (int r = 0; r < 4; ++r) {
                    float mn = fmaxf(mrow[g][r], mx2[r]);
                    corr[r] = fexp2(mrow[g][r] - mn);
                    mrow[g][r] = mn;
                }
                #pragma unroll
                for (int f = 0; f < 4; ++f)
                    #pragma unroll
                    for (int r = 0; r < 4; ++r) o[g][f][r] *= corr[r];
                #pragma unroll
                for (int r = 0; r < 4; ++r) accl[g][r] *= corr[r];
            }
            unsigned short* pw = &Pl[w][g][0];
            #pragma unroll
            for (int f = 0; f < 4; ++f) {
                int key = f * 16 + lr;
                int khi2 = key >> 3, klo2 = key & 7;
                #pragma unroll
                for (int r = 0; r < 4; ++r) {
                    float p = fexp2(s[g][f][r] * SCL - mrow[g][r]);
                    union { float f; unsigned int i; } cv; cv.f = p;
                    int q = lg * 4 + r;
                    pw[q * 64 + ((khi2 ^ (q & 7)) << 3) + klo2] =
                        (unsigned short)((cv.i + 0x8000u) >> 16);
                }
            }
        }

        // ---- PV + row-sum, sharing each V-fragment read across groups ----
        __builtin_amdgcn_s_setprio(1);
        #pragma unroll
        for (int ck = 0; ck < 2; ++ck) {
            int kc = lg + 4 * ck;
            bf16x8 pa0, pa1;
            if (act0) {
                pa0 = __builtin_bit_cast(bf16x8,
                    *(const u32x4*)&Pl[w][0][lr * 64 + ((kc ^ (lr & 7)) << 3)]);
                accl[0] = __builtin_amdgcn_mfma_f32_16x16x32_bf16(pa0, onesf, accl[0], 0, 0, 0);
            }
            pa1 = __builtin_bit_cast(bf16x8,
                *(const u32x4*)&Pl[w][1][lr * 64 + ((kc ^ (lr & 7)) << 3)]);
            accl[1] = __builtin_amdgcn_mfma_f32_16x16x32_bf16(pa1, onesf, accl[1], 0, 0, 0);
            #pragma unroll
            for (int f = 0; f < 4; ++f) {
                int dh = f * 16 + lr;
                bf16x8 vb = __builtin_bit_cast(bf16x8,
                    *(const u32x4*)&Vt[dh * 64 + ((kc ^ (dh & 7)) << 3)]);
                if (act0) o[0][f] = __builtin_amdgcn_mfma_f32_16x16x32_bf16(pa0, vb, o[0][f], 0, 0, 0);
                o[1][f] = __builtin_amdgcn_mfma_f32_16x16x32_bf16(pa1, vb, o[1][f], 0, 0, 0);
            }
        }
        __builtin_amdgcn_s_setprio(0);
    }

    // ---- epilogue (both groups) ----
    #pragma unroll
    for (int g = 0; g < 2; ++g) {
        float inv[4];
        #pragma unroll
        for (int r = 0; r < 4; ++r) inv[r] = 1.f / accl[g][r];
        #pragma unroll
        for (int f = 0; f < 4; ++f)
            #pragma unroll
            for (int r = 0; r < 4; ++r) {
                float v = o[g][f][r] * inv[r];
                Y[((size_t)(b * T_) + qw[g] + lg * 4 + r) * D_ + h * DH_ + f * 16 + lr] = f2bf(v);
            }
    }
}

extern "C" void kernel_launch(void* const* d_in, const int* in_sizes, int n_in,
                              void* d_out, int out_size, void* d_ws, size_t ws_size,
                              hipStream_t stream) {
    const float* x        = (const float*)d_in[0];
    const float* ctx      = (const float*)d_in[1];
    const float* W_qkv    = (const float*)d_in[2];
    const float* W_out_sa = (const float*)d_in[3];
    const float* b_out_sa = (const float*)d_in[4];
    const float* W_q      = (const float*)d_in[5];
    const float* W_kv     = (const float*)d_in[6];
    const float* W_out_ca = (const float*)d_in[7];
    const float* b_out_ca = (const float*)d_in[8];
    const float* W1       = (const float*)d_in[9];
    const float* b1       = (const float*)d_in[10];
    const float* W2       = (const float*)d_in[11];
    const float* b2       = (const float*)d_in[12];
    const float* g1  = (const float*)d_in[13];
    const float* bb1 = (const float*)d_in[14];
    const float* g2  = (const float*)d_in[15];
    const float* bb2 = (const float*)d_in[16];
    const float* g3  = (const float*)d_in[17];
    const float* bb3 = (const float*)d_in[18];

    char* ws = (char*)d_ws;
    size_t off = 0;
    auto alloc = [&](size_t bytes) { char* p = ws + off; off += (bytes + 255) & ~(size_t)255; return p; };

    unsigned short* wqkv_t = (unsigned short*)alloc(3072UL * 1024 * 2);
    unsigned short* wosa_t = (unsigned short*)alloc(1024UL * 1024 * 2);
    unsigned short* wq_t   = (unsigned short*)alloc(1024UL * 1024 * 2);
    unsigned short* wkv_t  = (unsigned short*)alloc(2048UL * 1024 * 2);
    unsigned short* woca_t = (unsigned short*)alloc(1024UL * 1024 * 2);
    unsigned short* w1_t   = (unsigned short*)alloc(4096UL * 1024 * 2);
    unsigned short* w2_t   = (unsigned short*)alloc(1024UL * 4096 * 2);
    unsigned short* h_bf   = (unsigned short*)alloc(4096UL * 1024 * 2);
    float*          x1     = (float*)alloc(4096UL * 1024 * 4);
    unsigned short* y_bf   = (unsigned short*)alloc(4096UL * 1024 * 2);
    unsigned short* qkv_bf = (unsigned short*)alloc(4096UL * 3072 * 2);
    unsigned short* qca_bf = (unsigned short*)alloc(4096UL * 1024 * 2);
    unsigned short* kv_bf  = (unsigned short*)alloc(4096UL * 2048 * 2);
    unsigned short* hc_bf  = (unsigned short*)alloc(4096UL * 1024 * 2);
    unsigned short* m1_bf  = qkv_bf;   // reuse: qkv+qca regions dead by MLP
    float* x2 = (float*)d_out;

    // weight transposes (f32 KxN -> bf16 NxK)
    transpose_w<<<dim3(3072/32, 1024/32), 256, 0, stream>>>(W_qkv,    wqkv_t, 1024, 3072);
    transpose_w<<<dim3(1024/32, 1024/32), 256, 0, stream>>>(W_out_sa, wosa_t, 1024, 1024);
    transpose_w<<<dim3(1024/32, 1024/32), 256, 0, stream>>>(W_q,      wq_t,   1024, 1024);
    transpose_w<<<dim3(2048/32, 1024/32), 256, 0, stream>>>(W_kv,     wkv_t,  1024, 2048);
    transpose_w<<<dim3(1024/32, 1024/32), 256, 0, stream>>>(W_out_ca, woca_t, 1024, 1024);
    transpose_w<<<dim3(4096/32, 1024/32), 256, 0, stream>>>(W1,       w1_t,   1024, 4096);
    transpose_w<<<dim3(1024/32, 4096/32), 256, 0, stream>>>(W2,       w2_t,   4096, 1024);

    // --- self-attention block ---
    ln_bf16<<<4096, 256, 0, stream>>>(x, g1, bb1, h_bf);
    gemm_bt<0><<<768, 256, 0, stream>>>(h_bf, wqkv_t, nullptr, qkv_bf, nullptr, nullptr, 4096, 3072, 1024, 24, 8);
    attn_mfma<true><<<dim3(16, 16, 2), 256, 0, stream>>>(qkv_bf, 3072, qkv_bf, 3072, 1024, 2048, y_bf, 2048);
    gemm_bt<2><<<256, 256, 0, stream>>>(y_bf, wosa_t, x1, nullptr, b_out_sa, x, 4096, 1024, 1024, 8, 8);

    // --- cross-attention block ---
    ln_bf16<<<4096, 256, 0, stream>>>(x1, g2, bb2, h_bf);
    gemm_bt<0><<<256, 256, 0, stream>>>(h_bf, wq_t, nullptr, qca_bf, nullptr, nullptr, 4096, 1024, 1024, 8, 8);
    cvt_f32_bf16<<<4096, 256, 0, stream>>>(ctx, hc_bf, 1048576);
    gemm_bt<0><<<512, 256, 0, stream>>>(hc_bf, wkv_t, nullptr, kv_bf, nullptr, nullptr, 4096, 2048, 1024, 16, 8);
    attn_mfma<false><<<dim3(16, 16, 2), 256, 0, stream>>>(qca_bf, 1024, kv_bf, 2048, 0, 1024, y_bf, 2048);
    gemm_bt<2><<<256, 256, 0, stream>>>(y_bf, woca_t, x2, nullptr, b_out_ca, x1, 4096, 1024, 1024, 8, 8);

    // --- MLP block ---
    ln_bf16<<<4096, 256, 0, stream>>>(x2, g3, bb3, h_bf);
    gemm_bt<1><<<1024, 256, 0, stream>>>(h_bf, w1_t, nullptr, m1_bf, b1, nullptr, 4096, 4096, 1024, 32, 8);
    gemm_bt<2><<<256, 256, 0, stream>>>(m1_bf, w2_t, (float*)d_out, nullptr, b2, x2, 4096, 1024, 4096, 8, 2);
}

// Round 13
// 449.733 us; speedup vs baseline: 1.0595x; 1.0086x over previous
//
#include <hip/hip_runtime.h>
#include <hip/hip_bf16.h>

#define D_   1024
#define NH_  16
#define DH_  64
#define T_   2048
#define S_   2048
#define B_   2
#define FF_  4096

typedef __bf16 bf16x8 __attribute__((ext_vector_type(8)));
typedef float  f32x4  __attribute__((ext_vector_type(4)));
typedef unsigned int u32x4 __attribute__((ext_vector_type(4)));

static __device__ __forceinline__ unsigned short f2bf(float f) {
    union { float f; unsigned int i; } v; v.f = f;
    unsigned int x = v.i;
    return (unsigned short)((x + 0x7fffu + ((x >> 16) & 1u)) >> 16);
}
static __device__ __forceinline__ float fexp2(float x) {
    return __builtin_amdgcn_exp2f(x);          // raw v_exp_f32 (fast, 1 VALU op)
}

// async global->LDS, 16B per lane; LDS dest is wave-uniform base + lane*16
static __device__ __forceinline__ void gld16(const unsigned short* g, unsigned short* l) {
    __builtin_amdgcn_global_load_lds(
        (const __attribute__((address_space(1))) void*)g,
        (__attribute__((address_space(3))) void*)l, 16, 0, 0);
}

// ---------------- weight transpose: W[K][N] f32 -> Wt[N][K] bf16 ----------------
__global__ __launch_bounds__(256) void transpose_w(const float* __restrict__ W,
                                                   unsigned short* __restrict__ Wt,
                                                   int K, int N) {
    __shared__ float tile[32][33];
    int n0 = blockIdx.x * 32, k0 = blockIdx.y * 32;
    int c = threadIdx.x & 31, r0 = threadIdx.x >> 5;
    #pragma unroll
    for (int i = 0; i < 4; ++i) {
        int r = r0 + i * 8;
        tile[r][c] = W[(size_t)(k0 + r) * N + n0 + c];
    }
    __syncthreads();
    #pragma unroll
    for (int i = 0; i < 4; ++i) {
        int r = r0 + i * 8;
        Wt[(size_t)(n0 + r) * K + k0 + c] = f2bf(tile[c][r]);
    }
}

// ---------------- LayerNorm (row of 1024 f32) -> bf16 ----------------
__global__ __launch_bounds__(256) void ln_bf16(const float* __restrict__ x,
                                               const float* __restrict__ g,
                                               const float* __restrict__ b,
                                               unsigned short* __restrict__ out) {
    int row = blockIdx.x;
    int t = threadIdx.x;
    const float4* xr = (const float4*)(x + (size_t)row * D_);
    float4 v = xr[t];
    float s = v.x + v.y + v.z + v.w;
    float s2 = v.x*v.x + v.y*v.y + v.z*v.z + v.w*v.w;
    #pragma unroll
    for (int o = 32; o > 0; o >>= 1) { s += __shfl_down(s, o); s2 += __shfl_down(s2, o); }
    __shared__ float red[8];
    int wid = t >> 6, lane = t & 63;
    if (lane == 0) { red[wid*2] = s; red[wid*2+1] = s2; }
    __syncthreads();
    float ts  = red[0] + red[2] + red[4] + red[6];
    float ts2 = red[1] + red[3] + red[5] + red[7];
    float mu = ts * (1.0f / D_);
    float var = ts2 * (1.0f / D_) - mu * mu;
    float rstd = rsqrtf(var + 1e-5f);
    float4 gv = ((const float4*)g)[t];
    float4 bv = ((const float4*)b)[t];
    ushort4 o4;
    o4.x = f2bf((v.x - mu) * rstd * gv.x + bv.x);
    o4.y = f2bf((v.y - mu) * rstd * gv.y + bv.y);
    o4.z = f2bf((v.z - mu) * rstd * gv.z + bv.z);
    o4.w = f2bf((v.w - mu) * rstd * gv.w + bv.w);
    ((ushort4*)(out + (size_t)row * D_))[t] = o4;
}

// ---------------- f32 -> bf16 convert ----------------
__global__ __launch_bounds__(256) void cvt_f32_bf16(const float* __restrict__ in,
                                                    unsigned short* __restrict__ out, int n4) {
    int i = blockIdx.x * 256 + threadIdx.x;
    if (i < n4) {
        float4 v = ((const float4*)in)[i];
        ushort4 o; o.x = f2bf(v.x); o.y = f2bf(v.y); o.z = f2bf(v.z); o.w = f2bf(v.w);
        ((ushort4*)out)[i] = o;
    }
}

// ---------------- GEMM: C[M][N] = A[M][K](bf16) @ Bt[N][K]^T (bf16) ----------------
// L2 rasterization (round 5) + double-buffer with COUNTED vmcnt (T3+T4, this round):
// per iter: issue 4 gld16 for t+1 into buf^1 (8 outstanding), s_waitcnt vmcnt(4)
// (waits only for buf[cur]'s loads, issued a FULL iteration earlier), barrier,
// compute, barrier. Loads stay in flight across an entire iteration instead of
// draining to 0 each step. Last iter: vmcnt(0) (nothing newly issued — vmcnt(4)
// would fall through with exactly 4 outstanding).
// Hazards: L(t+1) targets the unread buffer; L(t+2) issue happens only after the
// 2nd barrier of t (all reads of buf[cur] complete, lgkmcnt-enforced before MFMA).
// EPI 0: bf16 out, no bias | 1: bf16 out, +bias, relu | 2: f32 out, +bias, +residual
template<int EPI>
__global__ __launch_bounds__(256) void gemm_bt(const unsigned short* __restrict__ A,
                                               const unsigned short* __restrict__ Bt,
                                               float* __restrict__ Cf,
                                               unsigned short* __restrict__ Cb,
                                               const float* __restrict__ bias,
                                               const float* __restrict__ resid,
                                               int M, int N, int K, int gn, int nb) {
    __shared__ unsigned short As[2][128 * 32];
    __shared__ unsigned short Bs[2][128 * 32];
    int tid = threadIdx.x;
    int lane = tid & 63, wv = tid >> 6;
    int wm = wv >> 1, wn = wv & 1;
    int lr = lane & 15, lg = lane >> 4;

    int bid = blockIdx.x, nwg = gridDim.x;
    int q8 = nwg >> 3, r8 = nwg & 7;
    int xcd = bid & 7, idx = bid >> 3;
    int wg = (xcd < r8 ? xcd * (q8 + 1) : r8 * (q8 + 1) + (xcd - r8) * q8) + idx;
    int gm = nwg / gn;
    int bandsz = gm * nb;
    int band = wg / bandsz;
    int rem = wg - band * bandsz;
    int mt = rem / nb;
    int nt = band * nb + (rem - mt * nb);
    int m0 = mt * 128, n0 = nt * 128;

    int csw = ((lane & 3) ^ ((lane >> 3) & 3)) * 8;
    const unsigned short* aSrc[2];
    const unsigned short* bSrc[2];
    int dOff[2];
    #pragma unroll
    for (int i = 0; i < 2; ++i) {
        int rblk = wv * 2 + i;
        int row = rblk * 16 + (lane >> 2);
        aSrc[i] = A  + (size_t)(m0 + row) * K + csw;
        bSrc[i] = Bt + (size_t)(n0 + row) * K + csw;
        dOff[i] = rblk * 512;
    }

    const f32x4 vzero = {0.f, 0.f, 0.f, 0.f};
    f32x4 acc[4][4];
    #pragma unroll
    for (int i = 0; i < 4; ++i)
        #pragma unroll
        for (int j = 0; j < 4; ++j) acc[i][j] = vzero;

    const int nsteps = K >> 5;   // K/32

    // prologue: stage K-step 0 into buffer 0 (stays in flight until iter 0's wait)
    #pragma unroll
    for (int i = 0; i < 2; ++i) {
        gld16(aSrc[i], &As[0][dOff[i]]);
        gld16(bSrc[i], &Bs[0][dOff[i]]);
    }

    int cur = 0;
    for (int t = 0; t < nsteps; ++t) {
        // issue next-step prefetch into the other buffer, then wait ONLY for
        // the current buffer's loads (counted vmcnt keeps prefetch in flight)
        if (t + 1 < nsteps) {
            int k0n = (t + 1) << 5;
            #pragma unroll
            for (int i = 0; i < 2; ++i) {
                gld16(aSrc[i] + k0n, &As[cur ^ 1][dOff[i]]);
                gld16(bSrc[i] + k0n, &Bs[cur ^ 1][dOff[i]]);
            }
            asm volatile("s_waitcnt vmcnt(4)" ::: "memory");
        } else {
            asm volatile("s_waitcnt vmcnt(0)" ::: "memory");
        }
        __builtin_amdgcn_s_barrier();
        // compute current buffer
        bf16x8 a[4], b[4];
        #pragma unroll
        for (int f = 0; f < 4; ++f) {
            int ra = wm * 64 + f * 16 + lr;
            a[f] = __builtin_bit_cast(bf16x8, *(const u32x4*)&As[cur][ra * 32 + ((lg ^ ((ra >> 1) & 3)) << 3)]);
            int rb = wn * 64 + f * 16 + lr;
            b[f] = __builtin_bit_cast(bf16x8, *(const u32x4*)&Bs[cur][rb * 32 + ((lg ^ ((rb >> 1) & 3)) << 3)]);
        }
        __builtin_amdgcn_s_setprio(1);
        #pragma unroll
        for (int i = 0; i < 4; ++i)
            #pragma unroll
            for (int j = 0; j < 4; ++j)
                acc[i][j] = __builtin_amdgcn_mfma_f32_16x16x32_bf16(a[i], b[j], acc[i][j], 0, 0, 0);
        __builtin_amdgcn_s_setprio(0);
        // release buf[cur] for the t+2 prefetch (issued after this barrier)
        __builtin_amdgcn_s_barrier();
        cur ^= 1;
    }

    #pragma unroll
    for (int i = 0; i < 4; ++i) {
        int rbase = m0 + wm * 64 + i * 16 + lg * 4;
        #pragma unroll
        for (int j = 0; j < 4; ++j) {
            int col = n0 + wn * 64 + j * 16 + lr;
            #pragma unroll
            for (int r = 0; r < 4; ++r) {
                int row = rbase + r;
                float v = acc[i][j][r];
                if (EPI == 0) {
                    Cb[(size_t)row * N + col] = f2bf(v);
                } else if (EPI == 1) {
                    v += bias[col];
                    v = v > 0.f ? v : 0.f;
                    Cb[(size_t)row * N + col] = f2bf(v);
                } else {
                    v += bias[col] + resid[(size_t)row * N + col];
                    Cf[(size_t)row * N + col] = v;
                }
            }
        }
    }
}

// ---------------- MFMA flash attention, 32 q-rows per wave (2 groups of 16) ----------------
// Round-11 verified structure, UNCHANGED.
// NOTE: launch_bounds MUST stay (256,2) — unified VGPR+AGPR need ~160/wave; higher
// min-waves caps regs below need and spills (round3 (256,6)=435us; round5 (256,4)=295us).
template<bool CAUSAL>
__global__ __launch_bounds__(256, 2) void attn_mfma(
    const unsigned short* __restrict__ Qsrc, int q_stride,
    const unsigned short* __restrict__ KVsrc, int kv_stride,
    int k_off0, int v_off0,
    unsigned short* __restrict__ Y, int Lk)
{
    __shared__ unsigned short Kl[64 * 64];        // [key][dh], chunk c=dh>>3 at c^(key&7)
    __shared__ unsigned short Vt[64 * 64];        // [dh][key], chunk c=key>>3 at c^(dh&7)
    __shared__ unsigned short Pl[4][2][16 * 64];  // per-wave, per-group [q][key], chunk c^(q&7)

    const float SCL = 0.125f * 1.44269504f;       // 1/sqrt(DH) * log2(e)

    const int tid = threadIdx.x;
    const int lane = tid & 63, w = tid >> 6;
    const int lr = lane & 15, lg = lane >> 4;
    const int h = blockIdx.y, b = blockIdx.z;
    const int bx = blockIdx.x;

    int qw[2];
    if (CAUSAL) {
        qw[0] = bx * 64 + w * 16;
        qw[1] = (2 * (int)gridDim.x - 1 - bx) * 64 + w * 16;
    } else {
        qw[0] = bx * 128 + w * 16;
        qw[1] = bx * 128 + 64 + w * 16;
    }
    const int ntiles = CAUSAL ? (2 * (int)gridDim.x - bx) : (Lk / 64);

    bf16x8 qf[2][2];
    #pragma unroll
    for (int g = 0; g < 2; ++g) {
        const unsigned short* qp = Qsrc + ((size_t)(b * T_) + qw[g] + lr) * q_stride + h * DH_ + lg * 8;
        qf[g][0] = __builtin_bit_cast(bf16x8, *(const u32x4*)qp);
        qf[g][1] = __builtin_bit_cast(bf16x8, *(const u32x4*)(qp + 32));
    }
    bf16x8 onesf;
    #pragma unroll
    for (int i = 0; i < 8; ++i) onesf[i] = (__bf16)1.0f;

    f32x4 o[2][4];
    f32x4 accl[2];
    float mrow[2][4];                 // running max in log2 domain
    #pragma unroll
    for (int g = 0; g < 2; ++g) {
        #pragma unroll
        for (int f = 0; f < 4; ++f) o[g][f] = {0.f, 0.f, 0.f, 0.f};
        accl[g] = {0.f, 0.f, 0.f, 0.f};
        #pragma unroll
        for (int r = 0; r < 4; ++r) mrow[g][r] = -3e38f;
    }

    // staging thread mappings (block-constant)
    const int kkey = tid >> 2, kdc = (tid & 3) * 2;   // K: 4 threads/key, 2x16B chunks each
    const unsigned short* kbase = KVsrc + ((size_t)(b * Lk) + kkey) * kv_stride + k_off0 + h * DH_ + kdc * 8;
    const int vkey = lane;                            // V: key per lane; wave w -> dh chunks {w, w+4}
    const unsigned short* vbase = KVsrc + ((size_t)(b * Lk) + vkey) * kv_stride + v_off0 + h * DH_;

    u32x4 kr0 = *(const u32x4*)kbase;
    u32x4 kr1 = *(const u32x4*)(kbase + 8);
    u32x4 vr0 = *(const u32x4*)(vbase + w * 8);
    u32x4 vr1 = *(const u32x4*)(vbase + (w + 4) * 8);

    for (int t = 0; t < ntiles; ++t) {
        const int k0 = t * 64;
        __syncthreads();
        // ---- write staged registers to LDS ----
        {
            int s0 = (kdc    ) ^ (kkey & 7);
            int s1 = (kdc + 1) ^ (kkey & 7);
            *(u32x4*)&Kl[kkey * 64 + s0 * 8] = kr0;
            *(u32x4*)&Kl[kkey * 64 + s1 * 8] = kr1;
        }
        {
            const unsigned short* u0 = (const unsigned short*)&vr0;
            const unsigned short* u1 = (const unsigned short*)&vr1;
            int khi = vkey >> 3, klo = vkey & 7;
            #pragma unroll
            for (int j = 0; j < 8; ++j) {
                Vt[(w * 8 + j)       * 64 + ((khi ^ j) << 3) + klo] = u0[j];
                Vt[((w + 4) * 8 + j) * 64 + ((khi ^ j) << 3) + klo] = u1[j];
            }
        }
        __syncthreads();
        // ---- prefetch next tile into registers ----
        if (t + 1 < ntiles) {
            const unsigned short* kp = kbase + (size_t)(k0 + 64) * kv_stride;
            kr0 = *(const u32x4*)kp;
            kr1 = *(const u32x4*)(kp + 8);
            const unsigned short* vp = vbase + (size_t)(k0 + 64) * kv_stride;
            vr0 = *(const u32x4*)(vp + w * 8);
            vr1 = *(const u32x4*)(vp + (w + 4) * 8);
        }
        const bool act0 = !CAUSAL || (t <= bx);   // group1 always active

        // ---- QK^T for both groups, sharing each K-fragment read ----
        f32x4 s[2][4];
        #pragma unroll
        for (int g = 0; g < 2; ++g)
            #pragma unroll
            for (int f = 0; f < 4; ++f) s[g][f] = {0.f, 0.f, 0.f, 0.f};
        __builtin_amdgcn_s_setprio(1);
        #pragma unroll
        for (int ck = 0; ck < 2; ++ck) {
            int kc = lg + 4 * ck;
            #pragma unroll
            for (int f = 0; f < 4; ++f) {
                int key = f * 16 + lr;
                bf16x8 kb = __builtin_bit_cast(bf16x8,
                    *(const u32x4*)&Kl[key * 64 + ((kc ^ (key & 7)) << 3)]);
                if (act0) s[0][f] = __builtin_amdgcn_mfma_f32_16x16x32_bf16(qf[0][ck], kb, s[0][f], 0, 0, 0);
                s[1][f] = __builtin_amdgcn_mfma_f32_16x16x32_bf16(qf[1][ck], kb, s[1][f], 0, 0, 0);
            }
        }
        __builtin_amdgcn_s_setprio(0);

        // ---- per-group: mask, online softmax (log2 domain, defer-max), P pack+store ----
        #pragma unroll
        for (int g = 0; g < 2; ++g) {
            if (g == 0 && !act0) continue;
            if (CAUSAL && (k0 + 63 > qw[g])) {
                int dq = qw[g] + lg * 4 - k0 - lr;   // mask if f*16 - r > dq
                #pragma unroll
                for (int f = 0; f < 4; ++f)
                    #pragma unroll
                    for (int r = 0; r < 4; ++r)
                        s[g][f][r] = (f * 16 - r > dq) ? -3e38f : s[g][f][r];
            }
            float mx2[4];
            #pragma unroll
            for (int r = 0; r < 4; ++r) {
                float mx = fmaxf(fmaxf(s[g][0][r], s[g][1][r]), fmaxf(s[g][2][r], s[g][3][r]));
                mx = fmaxf(mx, __shfl_xor(mx, 1));
                mx = fmaxf(mx, __shfl_xor(mx, 2));
                mx = fmaxf(mx, __shfl_xor(mx, 4));
                mx = fmaxf(mx, __shfl_xor(mx, 8));
                mx2[r] = mx * SCL;
            }
            bool need = false;
            #pragma unroll
            for (int r = 0; r < 4; ++r) need = need || (mx2[r] > mrow[g][r] + 8.0f);
            if (__any(need ? 1 : 0)) {
                float corr[4];
                #pragma unroll
                for (int r = 0; r < 4; ++r) {
                    float mn = fmaxf(mrow[g][r], mx2[r]);
                    corr[r] = fexp2(mrow[g][r] - mn);
                    mrow[g][r] = mn;
                }
                #pragma unroll
                for (int f = 0; f < 4; ++f)
                    #pragma unroll
                    for (int r = 0; r < 4; ++r) o[g][f][r] *= corr[r];
                #pragma unroll
                for (int r = 0; r < 4; ++r) accl[g][r] *= corr[r];
            }
            unsigned short* pw = &Pl[w][g][0];
            #pragma unroll
            for (int f = 0; f < 4; ++f) {
                int key = f * 16 + lr;
                int khi2 = key >> 3, klo2 = key & 7;
                #pragma unroll
                for (int r = 0; r < 4; ++r) {
                    float p = fexp2(s[g][f][r] * SCL - mrow[g][r]);
                    union { float f; unsigned int i; } cv; cv.f = p;
                    int q = lg * 4 + r;
                    pw[q * 64 + ((khi2 ^ (q & 7)) << 3) + klo2] =
                        (unsigned short)((cv.i + 0x8000u) >> 16);
                }
            }
        }

        // ---- PV + row-sum, sharing each V-fragment read across groups ----
        __builtin_amdgcn_s_setprio(1);
        #pragma unroll
        for (int ck = 0; ck < 2; ++ck) {
            int kc = lg + 4 * ck;
            bf16x8 pa0, pa1;
            if (act0) {
                pa0 = __builtin_bit_cast(bf16x8,
                    *(const u32x4*)&Pl[w][0][lr * 64 + ((kc ^ (lr & 7)) << 3)]);
                accl[0] = __builtin_amdgcn_mfma_f32_16x16x32_bf16(pa0, onesf, accl[0], 0, 0, 0);
            }
            pa1 = __builtin_bit_cast(bf16x8,
                *(const u32x4*)&Pl[w][1][lr * 64 + ((kc ^ (lr & 7)) << 3)]);
            accl[1] = __builtin_amdgcn_mfma_f32_16x16x32_bf16(pa1, onesf, accl[1], 0, 0, 0);
            #pragma unroll
            for (int f = 0; f < 4; ++f) {
                int dh = f * 16 + lr;
                bf16x8 vb = __builtin_bit_cast(bf16x8,
                    *(const u32x4*)&Vt[dh * 64 + ((kc ^ (dh & 7)) << 3)]);
                if (act0) o[0][f] = __builtin_amdgcn_mfma_f32_16x16x32_bf16(pa0, vb, o[0][f], 0, 0, 0);
                o[1][f] = __builtin_amdgcn_mfma_f32_16x16x32_bf16(pa1, vb, o[1][f], 0, 0, 0);
            }
        }
        __builtin_amdgcn_s_setprio(0);
    }

    // ---- epilogue (both groups) ----
    #pragma unroll
    for (int g = 0; g < 2; ++g) {
        float inv[4];
        #pragma unroll
        for (int r = 0; r < 4; ++r) inv[r] = 1.f / accl[g][r];
        #pragma unroll
        for (int f = 0; f < 4; ++f)
            #pragma unroll
            for (int r = 0; r < 4; ++r) {
                float v = o[g][f][r] * inv[r];
                Y[((size_t)(b * T_) + qw[g] + lg * 4 + r) * D_ + h * DH_ + f * 16 + lr] = f2bf(v);
            }
    }
}

extern "C" void kernel_launch(void* const* d_in, const int* in_sizes, int n_in,
                              void* d_out, int out_size, void* d_ws, size_t ws_size,
                              hipStream_t stream) {
    const float* x        = (const float*)d_in[0];
    const float* ctx      = (const float*)d_in[1];
    const float* W_qkv    = (const float*)d_in[2];
    const float* W_out_sa = (const float*)d_in[3];
    const float* b_out_sa = (const float*)d_in[4];
    const float* W_q      = (const float*)d_in[5];
    const float* W_kv     = (const float*)d_in[6];
    const float* W_out_ca = (const float*)d_in[7];
    const float* b_out_ca = (const float*)d_in[8];
    const float* W1       = (const float*)d_in[9];
    const float* b1       = (const float*)d_in[10];
    const float* W2       = (const float*)d_in[11];
    const float* b2       = (const float*)d_in[12];
    const float* g1  = (const float*)d_in[13];
    const float* bb1 = (const float*)d_in[14];
    const float* g2  = (const float*)d_in[15];
    const float* bb2 = (const float*)d_in[16];
    const float* g3  = (const float*)d_in[17];
    const float* bb3 = (const float*)d_in[18];

    char* ws = (char*)d_ws;
    size_t off = 0;
    auto alloc = [&](size_t bytes) { char* p = ws + off; off += (bytes + 255) & ~(size_t)255; return p; };

    unsigned short* wqkv_t = (unsigned short*)alloc(3072UL * 1024 * 2);
    unsigned short* wosa_t = (unsigned short*)alloc(1024UL * 1024 * 2);
    unsigned short* wq_t   = (unsigned short*)alloc(1024UL * 1024 * 2);
    unsigned short* wkv_t  = (unsigned short*)alloc(2048UL * 1024 * 2);
    unsigned short* woca_t = (unsigned short*)alloc(1024UL * 1024 * 2);
    unsigned short* w1_t   = (unsigned short*)alloc(4096UL * 1024 * 2);
    unsigned short* w2_t   = (unsigned short*)alloc(1024UL * 4096 * 2);
    unsigned short* h_bf   = (unsigned short*)alloc(4096UL * 1024 * 2);
    float*          x1     = (float*)alloc(4096UL * 1024 * 4);
    unsigned short* y_bf   = (unsigned short*)alloc(4096UL * 1024 * 2);
    unsigned short* qkv_bf = (unsigned short*)alloc(4096UL * 3072 * 2);
    unsigned short* qca_bf = (unsigned short*)alloc(4096UL * 1024 * 2);
    unsigned short* kv_bf  = (unsigned short*)alloc(4096UL * 2048 * 2);
    unsigned short* hc_bf  = (unsigned short*)alloc(4096UL * 1024 * 2);
    unsigned short* m1_bf  = qkv_bf;   // reuse: qkv+qca regions dead by MLP
    float* x2 = (float*)d_out;

    // weight transposes (f32 KxN -> bf16 NxK)
    transpose_w<<<dim3(3072/32, 1024/32), 256, 0, stream>>>(W_qkv,    wqkv_t, 1024, 3072);
    transpose_w<<<dim3(1024/32, 1024/32), 256, 0, stream>>>(W_out_sa, wosa_t, 1024, 1024);
    transpose_w<<<dim3(1024/32, 1024/32), 256, 0, stream>>>(W_q,      wq_t,   1024, 1024);
    transpose_w<<<dim3(2048/32, 1024/32), 256, 0, stream>>>(W_kv,     wkv_t,  1024, 2048);
    transpose_w<<<dim3(1024/32, 1024/32), 256, 0, stream>>>(W_out_ca, woca_t, 1024, 1024);
    transpose_w<<<dim3(4096/32, 1024/32), 256, 0, stream>>>(W1,       w1_t,   1024, 4096);
    transpose_w<<<dim3(1024/32, 4096/32), 256, 0, stream>>>(W2,       w2_t,   4096, 1024);

    // --- self-attention block ---
    ln_bf16<<<4096, 256, 0, stream>>>(x, g1, bb1, h_bf);
    gemm_bt<0><<<768, 256, 0, stream>>>(h_bf, wqkv_t, nullptr, qkv_bf, nullptr, nullptr, 4096, 3072, 1024, 24, 8);
    attn_mfma<true><<<dim3(16, 16, 2), 256, 0, stream>>>(qkv_bf, 3072, qkv_bf, 3072, 1024, 2048, y_bf, 2048);
    gemm_bt<2><<<256, 256, 0, stream>>>(y_bf, wosa_t, x1, nullptr, b_out_sa, x, 4096, 1024, 1024, 8, 8);

    // --- cross-attention block ---
    ln_bf16<<<4096, 256, 0, stream>>>(x1, g2, bb2, h_bf);
    gemm_bt<0><<<256, 256, 0, stream>>>(h_bf, wq_t, nullptr, qca_bf, nullptr, nullptr, 4096, 1024, 1024, 8, 8);
    cvt_f32_bf16<<<4096, 256, 0, stream>>>(ctx, hc_bf, 1048576);
    gemm_bt<0><<<512, 256, 0, stream>>>(hc_bf, wkv_t, nullptr, kv_bf, nullptr, nullptr, 4096, 2048, 1024, 16, 8);
    attn_mfma<false><<<dim3(16, 16, 2), 256, 0, stream>>>(qca_bf, 1024, kv_bf, 2048, 0, 1024, y_bf, 2048);
    gemm_bt<2><<<256, 256, 0, stream>>>(y_bf, woca_t, x2, nullptr, b_out_ca, x1, 4096, 1024, 1024, 8, 8);

    // --- MLP block ---
    ln_bf16<<<4096, 256, 0, stream>>>(x2, g3, bb3, h_bf);
    gemm_bt<1><<<1024, 256, 0, stream>>>(h_bf, w1_t, nullptr, m1_bf, b1, nullptr, 4096, 4096, 1024, 32, 8);
    gemm_bt<2><<<256, 256, 0, stream>>>(m1_bf, w2_t, (float*)d_out, nullptr, b2, x2, 4096, 1024, 4096, 8, 2);
}

// Round 14
// 412.822 us; speedup vs baseline: 1.1542x; 1.0894x over previous
//
#include <hip/hip_runtime.h>
#include <hip/hip_bf16.h>

#define D_   1024
#define NH_  16
#define DH_  64
#define T_   2048
#define S_   2048
#define B_   2
#define FF_  4096

typedef __bf16 bf16x8 __attribute__((ext_vector_type(8)));
typedef float  f32x4  __attribute__((ext_vector_type(4)));
typedef unsigned int u32x4 __attribute__((ext_vector_type(4)));

static __device__ __forceinline__ unsigned short f2bf(float f) {
    union { float f; unsigned int i; } v; v.f = f;
    unsigned int x = v.i;
    return (unsigned short)((x + 0x7fffu + ((x >> 16) & 1u)) >> 16);
}
static __device__ __forceinline__ float fexp2(float x) {
    return __builtin_amdgcn_exp2f(x);          // raw v_exp_f32 (fast, 1 VALU op)
}

// async global->LDS, 16B per lane; LDS dest is wave-uniform base + lane*16
static __device__ __forceinline__ void gld16(const unsigned short* g, unsigned short* l) {
    __builtin_amdgcn_global_load_lds(
        (const __attribute__((address_space(1))) void*)g,
        (__attribute__((address_space(3))) void*)l, 16, 0, 0);
}

// ---------------- weight transpose: W[K][N] f32 -> Wt[N][K] bf16 ----------------
__global__ __launch_bounds__(256) void transpose_w(const float* __restrict__ W,
                                                   unsigned short* __restrict__ Wt,
                                                   int K, int N) {
    __shared__ float tile[32][33];
    int n0 = blockIdx.x * 32, k0 = blockIdx.y * 32;
    int c = threadIdx.x & 31, r0 = threadIdx.x >> 5;
    #pragma unroll
    for (int i = 0; i < 4; ++i) {
        int r = r0 + i * 8;
        tile[r][c] = W[(size_t)(k0 + r) * N + n0 + c];
    }
    __syncthreads();
    #pragma unroll
    for (int i = 0; i < 4; ++i) {
        int r = r0 + i * 8;
        Wt[(size_t)(n0 + r) * K + k0 + c] = f2bf(tile[c][r]);
    }
}

// ---------------- LayerNorm (row of 1024 f32) -> bf16 ----------------
__global__ __launch_bounds__(256) void ln_bf16(const float* __restrict__ x,
                                               const float* __restrict__ g,
                                               const float* __restrict__ b,
                                               unsigned short* __restrict__ out) {
    int row = blockIdx.x;
    int t = threadIdx.x;
    const float4* xr = (const float4*)(x + (size_t)row * D_);
    float4 v = xr[t];
    float s = v.x + v.y + v.z + v.w;
    float s2 = v.x*v.x + v.y*v.y + v.z*v.z + v.w*v.w;
    #pragma unroll
    for (int o = 32; o > 0; o >>= 1) { s += __shfl_down(s, o); s2 += __shfl_down(s2, o); }
    __shared__ float red[8];
    int wid = t >> 6, lane = t & 63;
    if (lane == 0) { red[wid*2] = s; red[wid*2+1] = s2; }
    __syncthreads();
    float ts  = red[0] + red[2] + red[4] + red[6];
    float ts2 = red[1] + red[3] + red[5] + red[7];
    float mu = ts * (1.0f / D_);
    float var = ts2 * (1.0f / D_) - mu * mu;
    float rstd = rsqrtf(var + 1e-5f);
    float4 gv = ((const float4*)g)[t];
    float4 bv = ((const float4*)b)[t];
    ushort4 o4;
    o4.x = f2bf((v.x - mu) * rstd * gv.x + bv.x);
    o4.y = f2bf((v.y - mu) * rstd * gv.y + bv.y);
    o4.z = f2bf((v.z - mu) * rstd * gv.z + bv.z);
    o4.w = f2bf((v.w - mu) * rstd * gv.w + bv.w);
    ((ushort4*)(out + (size_t)row * D_))[t] = o4;
}

// ---------------- f32 -> bf16 convert ----------------
__global__ __launch_bounds__(256) void cvt_f32_bf16(const float* __restrict__ in,
                                                    unsigned short* __restrict__ out, int n4) {
    int i = blockIdx.x * 256 + threadIdx.x;
    if (i < n4) {
        float4 v = ((const float4*)in)[i];
        ushort4 o; o.x = f2bf(v.x); o.y = f2bf(v.y); o.z = f2bf(v.z); o.w = f2bf(v.w);
        ((ushort4*)out)[i] = o;
    }
}

// ---------------- GEMM: C[M][N] = A[M][K](bf16) @ Bt[N][K]^T (bf16) ----------------
// Round-13 verified: L2 rasterization + double-buffer with counted vmcnt. UNCHANGED.
template<int EPI>
__global__ __launch_bounds__(256) void gemm_bt(const unsigned short* __restrict__ A,
                                               const unsigned short* __restrict__ Bt,
                                               float* __restrict__ Cf,
                                               unsigned short* __restrict__ Cb,
                                               const float* __restrict__ bias,
                                               const float* __restrict__ resid,
                                               int M, int N, int K, int gn, int nb) {
    __shared__ unsigned short As[2][128 * 32];
    __shared__ unsigned short Bs[2][128 * 32];
    int tid = threadIdx.x;
    int lane = tid & 63, wv = tid >> 6;
    int wm = wv >> 1, wn = wv & 1;
    int lr = lane & 15, lg = lane >> 4;

    int bid = blockIdx.x, nwg = gridDim.x;
    int q8 = nwg >> 3, r8 = nwg & 7;
    int xcd = bid & 7, idx = bid >> 3;
    int wg = (xcd < r8 ? xcd * (q8 + 1) : r8 * (q8 + 1) + (xcd - r8) * q8) + idx;
    int gm = nwg / gn;
    int bandsz = gm * nb;
    int band = wg / bandsz;
    int rem = wg - band * bandsz;
    int mt = rem / nb;
    int nt = band * nb + (rem - mt * nb);
    int m0 = mt * 128, n0 = nt * 128;

    int csw = ((lane & 3) ^ ((lane >> 3) & 3)) * 8;
    const unsigned short* aSrc[2];
    const unsigned short* bSrc[2];
    int dOff[2];
    #pragma unroll
    for (int i = 0; i < 2; ++i) {
        int rblk = wv * 2 + i;
        int row = rblk * 16 + (lane >> 2);
        aSrc[i] = A  + (size_t)(m0 + row) * K + csw;
        bSrc[i] = Bt + (size_t)(n0 + row) * K + csw;
        dOff[i] = rblk * 512;
    }

    const f32x4 vzero = {0.f, 0.f, 0.f, 0.f};
    f32x4 acc[4][4];
    #pragma unroll
    for (int i = 0; i < 4; ++i)
        #pragma unroll
        for (int j = 0; j < 4; ++j) acc[i][j] = vzero;

    const int nsteps = K >> 5;   // K/32

    // prologue: stage K-step 0 into buffer 0 (stays in flight until iter 0's wait)
    #pragma unroll
    for (int i = 0; i < 2; ++i) {
        gld16(aSrc[i], &As[0][dOff[i]]);
        gld16(bSrc[i], &Bs[0][dOff[i]]);
    }

    int cur = 0;
    for (int t = 0; t < nsteps; ++t) {
        if (t + 1 < nsteps) {
            int k0n = (t + 1) << 5;
            #pragma unroll
            for (int i = 0; i < 2; ++i) {
                gld16(aSrc[i] + k0n, &As[cur ^ 1][dOff[i]]);
                gld16(bSrc[i] + k0n, &Bs[cur ^ 1][dOff[i]]);
            }
            asm volatile("s_waitcnt vmcnt(4)" ::: "memory");
        } else {
            asm volatile("s_waitcnt vmcnt(0)" ::: "memory");
        }
        __builtin_amdgcn_s_barrier();
        bf16x8 a[4], b[4];
        #pragma unroll
        for (int f = 0; f < 4; ++f) {
            int ra = wm * 64 + f * 16 + lr;
            a[f] = __builtin_bit_cast(bf16x8, *(const u32x4*)&As[cur][ra * 32 + ((lg ^ ((ra >> 1) & 3)) << 3)]);
            int rb = wn * 64 + f * 16 + lr;
            b[f] = __builtin_bit_cast(bf16x8, *(const u32x4*)&Bs[cur][rb * 32 + ((lg ^ ((rb >> 1) & 3)) << 3)]);
        }
        __builtin_amdgcn_s_setprio(1);
        #pragma unroll
        for (int i = 0; i < 4; ++i)
            #pragma unroll
            for (int j = 0; j < 4; ++j)
                acc[i][j] = __builtin_amdgcn_mfma_f32_16x16x32_bf16(a[i], b[j], acc[i][j], 0, 0, 0);
        __builtin_amdgcn_s_setprio(0);
        __builtin_amdgcn_s_barrier();
        cur ^= 1;
    }

    #pragma unroll
    for (int i = 0; i < 4; ++i) {
        int rbase = m0 + wm * 64 + i * 16 + lg * 4;
        #pragma unroll
        for (int j = 0; j < 4; ++j) {
            int col = n0 + wn * 64 + j * 16 + lr;
            #pragma unroll
            for (int r = 0; r < 4; ++r) {
                int row = rbase + r;
                float v = acc[i][j][r];
                if (EPI == 0) {
                    Cb[(size_t)row * N + col] = f2bf(v);
                } else if (EPI == 1) {
                    v += bias[col];
                    v = v > 0.f ? v : 0.f;
                    Cb[(size_t)row * N + col] = f2bf(v);
                } else {
                    v += bias[col] + resid[(size_t)row * N + col];
                    Cf[(size_t)row * N + col] = v;
                }
            }
        }
    }
}

// ---------------- MFMA flash attention, swapped-QK^T in-register softmax ----------------
// block = 256 threads (4 waves), 32 q-rows/wave (2 groups of 16).
// S^T = mfma(K, Q): lane (lr,lg) holds S[q=lr][key = kappa(f, lg*4+r)] where
// kappa = (f>>1)*32 + lg*8 + (f&1)*4 + r  — exactly keys {lg*8..+7, 32+lg*8..+7},
// i.e. this lane's own PV A-fragment keys. Softmax: 15 in-lane fmax + 2 shfl_xor
// (across lg); P packed IN REGISTERS via plain-C bf16 pack (round-7 retry: the
// inline-asm v_cvt_pk_bf16_f32 was the unverifiable primitive and m240 warns
// against it — now compiler-generated packing). No P LDS round-trip (saves
// ~40% of the DS-pipe per tile). K rows sigma-swizzled: sigma(krow)=lr&7.
// NOTE: launch_bounds MUST stay (256,2) — unified VGPR+AGPR ~176/wave; higher
// min-waves caps regs below need and spills (round3 (256,6)=435us; round5 (256,4)=295us).
template<bool CAUSAL>
__global__ __launch_bounds__(256, 2) void attn_mfma(
    const unsigned short* __restrict__ Qsrc, int q_stride,
    const unsigned short* __restrict__ KVsrc, int kv_stride,
    int k_off0, int v_off0,
    unsigned short* __restrict__ Y, int Lk)
{
    __shared__ unsigned short Kl[64 * 64];     // [key][dh], 16B chunk c at c ^ sigma(key)
    __shared__ unsigned short Vt[64 * 64];     // [dh][key], 16B chunk c at c ^ (dh&7)

    const float SCL = 0.125f * 1.44269504f;    // 1/sqrt(DH) * log2(e)

    const int tid = threadIdx.x;
    const int lane = tid & 63, w = tid >> 6;
    const int lr = lane & 15, lg = lane >> 4;
    const int h = blockIdx.y, b = blockIdx.z;
    const int bx = blockIdx.x;

    int qw[2];
    if (CAUSAL) {
        qw[0] = bx * 64 + w * 16;
        qw[1] = (2 * (int)gridDim.x - 1 - bx) * 64 + w * 16;
    } else {
        qw[0] = bx * 128 + w * 16;
        qw[1] = bx * 128 + 64 + w * 16;
    }
    const int ntiles = CAUSAL ? (2 * (int)gridDim.x - bx) : (Lk / 64);

    bf16x8 qf[2][2];
    #pragma unroll
    for (int g = 0; g < 2; ++g) {
        const unsigned short* qp = Qsrc + ((size_t)(b * T_) + qw[g] + lr) * q_stride + h * DH_ + lg * 8;
        qf[g][0] = __builtin_bit_cast(bf16x8, *(const u32x4*)qp);
        qf[g][1] = __builtin_bit_cast(bf16x8, *(const u32x4*)(qp + 32));
    }
    bf16x8 onesf;
    #pragma unroll
    for (int i = 0; i < 8; ++i) onesf[i] = (__bf16)1.0f;

    f32x4 o[2][4];                 // o[g][f][r] = Y[q=lg*4+r][dh=f*16+lr]
    f32x4 accl[2];                 // row-sum, same layout
    float mrow[2];                 // running max (log2 domain) for q = lr
    #pragma unroll
    for (int g = 0; g < 2; ++g) {
        #pragma unroll
        for (int f = 0; f < 4; ++f) o[g][f] = {0.f, 0.f, 0.f, 0.f};
        accl[g] = {0.f, 0.f, 0.f, 0.f};
        mrow[g] = -3e38f;
    }

    // staging thread mappings (block-constant)
    const int kkey = tid >> 2, kdc = (tid & 3) * 2;           // K: 4 threads/key, 2x16B chunks
    const int ksig = (kkey & 3) | (((kkey >> 3) & 1) << 2);   // sigma(key): bits {0,1,3}
    const unsigned short* kbase = KVsrc + ((size_t)(b * Lk) + kkey) * kv_stride + k_off0 + h * DH_ + kdc * 8;
    const int vkey = lane;                                    // V: key per lane; wave w -> dh chunks {w, w+4}
    const unsigned short* vbase = KVsrc + ((size_t)(b * Lk) + vkey) * kv_stride + v_off0 + h * DH_;

    u32x4 kr0 = *(const u32x4*)kbase;
    u32x4 kr1 = *(const u32x4*)(kbase + 8);
    u32x4 vr0 = *(const u32x4*)(vbase + w * 8);
    u32x4 vr1 = *(const u32x4*)(vbase + (w + 4) * 8);

    for (int t = 0; t < ntiles; ++t) {
        const int k0 = t * 64;
        __syncthreads();
        // ---- write staged registers to LDS ----
        {
            int s0 = (kdc    ) ^ ksig;
            int s1 = (kdc + 1) ^ ksig;
            *(u32x4*)&Kl[kkey * 64 + s0 * 8] = kr0;
            *(u32x4*)&Kl[kkey * 64 + s1 * 8] = kr1;
        }
        {
            const unsigned short* u0 = (const unsigned short*)&vr0;
            const unsigned short* u1 = (const unsigned short*)&vr1;
            int khi = vkey >> 3, klo = vkey & 7;
            #pragma unroll
            for (int j = 0; j < 8; ++j) {
                Vt[(w * 8 + j)       * 64 + ((khi ^ j) << 3) + klo] = u0[j];
                Vt[((w + 4) * 8 + j) * 64 + ((khi ^ j) << 3) + klo] = u1[j];
            }
        }
        __syncthreads();
        // ---- prefetch next tile into registers ----
        if (t + 1 < ntiles) {
            const unsigned short* kp = kbase + (size_t)(k0 + 64) * kv_stride;
            kr0 = *(const u32x4*)kp;
            kr1 = *(const u32x4*)(kp + 8);
            const unsigned short* vp = vbase + (size_t)(k0 + 64) * kv_stride;
            vr0 = *(const u32x4*)(vp + w * 8);
            vr1 = *(const u32x4*)(vp + (w + 4) * 8);
        }
        const bool act0 = !CAUSAL || (t <= bx);   // group1 always active

        // ---- QK^T swapped: s[g][f][r] = S[q=lr][key = (f>>1)*32 + lg*8 + (f&1)*4 + r] ----
        f32x4 s[2][4];
        #pragma unroll
        for (int g = 0; g < 2; ++g)
            #pragma unroll
            for (int f = 0; f < 4; ++f) s[g][f] = {0.f, 0.f, 0.f, 0.f};
        __builtin_amdgcn_s_setprio(1);
        #pragma unroll
        for (int ck = 0; ck < 2; ++ck) {
            int kc = lg + 4 * ck;
            #pragma unroll
            for (int f = 0; f < 4; ++f) {
                int krow = ((f >> 1) << 5) + ((lr >> 2) << 3) + ((f & 1) << 2) + (lr & 3);
                bf16x8 kb = __builtin_bit_cast(bf16x8,
                    *(const u32x4*)&Kl[krow * 64 + ((kc ^ (lr & 7)) << 3)]);
                if (act0) s[0][f] = __builtin_amdgcn_mfma_f32_16x16x32_bf16(kb, qf[0][ck], s[0][f], 0, 0, 0);
                s[1][f] = __builtin_amdgcn_mfma_f32_16x16x32_bf16(kb, qf[1][ck], s[1][f], 0, 0, 0);
            }
        }
        __builtin_amdgcn_s_setprio(0);

        // ---- per-group: mask, in-register softmax, P pack (own lane, plain C) ----
        unsigned int pk[2][4][2];
        #pragma unroll
        for (int g = 0; g < 2; ++g) {
            if (g == 0 && !act0) continue;
            if (CAUSAL && (k0 + 63 > qw[g])) {
                int dq = qw[g] + lr - k0 - lg * 8;   // mask if local key part > dq
                #pragma unroll
                for (int f = 0; f < 4; ++f)
                    #pragma unroll
                    for (int r = 0; r < 4; ++r) {
                        int kl = ((f >> 1) << 5) + ((f & 1) << 2) + r;
                        s[g][f][r] = (kl > dq) ? -3e38f : s[g][f][r];
                    }
            }
            float mx = s[g][0][0];
            #pragma unroll
            for (int f = 0; f < 4; ++f)
                #pragma unroll
                for (int r = 0; r < 4; ++r) mx = fmaxf(mx, s[g][f][r]);
            mx = fmaxf(mx, __shfl_xor(mx, 16));
            mx = fmaxf(mx, __shfl_xor(mx, 32));
            float mx2 = mx * SCL;
            if (__any(mx2 > mrow[g] + 8.0f)) {
                float mn = fmaxf(mrow[g], mx2);
                float corrq = fexp2(mrow[g] - mn);
                mrow[g] = mn;
                float co[4];
                #pragma unroll
                for (int r = 0; r < 4; ++r) co[r] = __shfl(corrq, lg * 4 + r);
                #pragma unroll
                for (int f = 0; f < 4; ++f)
                    #pragma unroll
                    for (int r = 0; r < 4; ++r) o[g][f][r] *= co[r];
                #pragma unroll
                for (int r = 0; r < 4; ++r) accl[g][r] *= co[r];
            }
            #pragma unroll
            for (int f = 0; f < 4; ++f)
                #pragma unroll
                for (int wd = 0; wd < 2; ++wd) {
                    float p0 = fexp2(s[g][f][2 * wd    ] * SCL - mrow[g]);
                    float p1 = fexp2(s[g][f][2 * wd + 1] * SCL - mrow[g]);
                    pk[g][f][wd] = ((unsigned int)f2bf(p1) << 16) | (unsigned int)f2bf(p0);
                }
        }

        // ---- PV + row-sum: pa assembled from own registers (no LDS) ----
        __builtin_amdgcn_s_setprio(1);
        #pragma unroll
        for (int ck = 0; ck < 2; ++ck) {
            int kc = lg + 4 * ck;
            bf16x8 pa0, pa1;
            if (act0) {
                u32x4 w0 = {pk[0][2 * ck][0], pk[0][2 * ck][1], pk[0][2 * ck + 1][0], pk[0][2 * ck + 1][1]};
                pa0 = __builtin_bit_cast(bf16x8, w0);
                accl[0] = __builtin_amdgcn_mfma_f32_16x16x32_bf16(pa0, onesf, accl[0], 0, 0, 0);
            }
            u32x4 w1 = {pk[1][2 * ck][0], pk[1][2 * ck][1], pk[1][2 * ck + 1][0], pk[1][2 * ck + 1][1]};
            pa1 = __builtin_bit_cast(bf16x8, w1);
            accl[1] = __builtin_amdgcn_mfma_f32_16x16x32_bf16(pa1, onesf, accl[1], 0, 0, 0);
            #pragma unroll
            for (int f = 0; f < 4; ++f) {
                int dh = f * 16 + lr;
                bf16x8 vb = __builtin_bit_cast(bf16x8,
                    *(const u32x4*)&Vt[dh * 64 + ((kc ^ (dh & 7)) << 3)]);
                if (act0) o[0][f] = __builtin_amdgcn_mfma_f32_16x16x32_bf16(pa0, vb, o[0][f], 0, 0, 0);
                o[1][f] = __builtin_amdgcn_mfma_f32_16x16x32_bf16(pa1, vb, o[1][f], 0, 0, 0);
            }
        }
        __builtin_amdgcn_s_setprio(0);
    }

    // ---- epilogue (both groups) ----
    #pragma unroll
    for (int g = 0; g < 2; ++g) {
        float inv[4];
        #pragma unroll
        for (int r = 0; r < 4; ++r) inv[r] = 1.f / accl[g][r];
        #pragma unroll
        for (int f = 0; f < 4; ++f)
            #pragma unroll
            for (int r = 0; r < 4; ++r) {
                float v = o[g][f][r] * inv[r];
                Y[((size_t)(b * T_) + qw[g] + lg * 4 + r) * D_ + h * DH_ + f * 16 + lr] = f2bf(v);
            }
    }
}

extern "C" void kernel_launch(void* const* d_in, const int* in_sizes, int n_in,
                              void* d_out, int out_size, void* d_ws, size_t ws_size,
                              hipStream_t stream) {
    const float* x        = (const float*)d_in[0];
    const float* ctx      = (const float*)d_in[1];
    const float* W_qkv    = (const float*)d_in[2];
    const float* W_out_sa = (const float*)d_in[3];
    const float* b_out_sa = (const float*)d_in[4];
    const float* W_q      = (const float*)d_in[5];
    const float* W_kv     = (const float*)d_in[6];
    const float* W_out_ca = (const float*)d_in[7];
    const float* b_out_ca = (const float*)d_in[8];
    const float* W1       = (const float*)d_in[9];
    const float* b1       = (const float*)d_in[10];
    const float* W2       = (const float*)d_in[11];
    const float* b2       = (const float*)d_in[12];
    const float* g1  = (const float*)d_in[13];
    const float* bb1 = (const float*)d_in[14];
    const float* g2  = (const float*)d_in[15];
    const float* bb2 = (const float*)d_in[16];
    const float* g3  = (const float*)d_in[17];
    const float* bb3 = (const float*)d_in[18];

    char* ws = (char*)d_ws;
    size_t off = 0;
    auto alloc = [&](size_t bytes) { char* p = ws + off; off += (bytes + 255) & ~(size_t)255; return p; };

    unsigned short* wqkv_t = (unsigned short*)alloc(3072UL * 1024 * 2);
    unsigned short* wosa_t = (unsigned short*)alloc(1024UL * 1024 * 2);
    unsigned short* wq_t   = (unsigned short*)alloc(1024UL * 1024 * 2);
    unsigned short* wkv_t  = (unsigned short*)alloc(2048UL * 1024 * 2);
    unsigned short* woca_t = (unsigned short*)alloc(1024UL * 1024 * 2);
    unsigned short* w1_t   = (unsigned short*)alloc(4096UL * 1024 * 2);
    unsigned short* w2_t   = (unsigned short*)alloc(1024UL * 4096 * 2);
    unsigned short* h_bf   = (unsigned short*)alloc(4096UL * 1024 * 2);
    float*          x1     = (float*)alloc(4096UL * 1024 * 4);
    unsigned short* y_bf   = (unsigned short*)alloc(4096UL * 1024 * 2);
    unsigned short* qkv_bf = (unsigned short*)alloc(4096UL * 3072 * 2);
    unsigned short* qca_bf = (unsigned short*)alloc(4096UL * 1024 * 2);
    unsigned short* kv_bf  = (unsigned short*)alloc(4096UL * 2048 * 2);
    unsigned short* hc_bf  = (unsigned short*)alloc(4096UL * 1024 * 2);
    unsigned short* m1_bf  = qkv_bf;   // reuse: qkv+qca regions dead by MLP
    float* x2 = (float*)d_out;

    // weight transposes (f32 KxN -> bf16 NxK)
    transpose_w<<<dim3(3072/32, 1024/32), 256, 0, stream>>>(W_qkv,    wqkv_t, 1024, 3072);
    transpose_w<<<dim3(1024/32, 1024/32), 256, 0, stream>>>(W_out_sa, wosa_t, 1024, 1024);
    transpose_w<<<dim3(1024/32, 1024/32), 256, 0, stream>>>(W_q,      wq_t,   1024, 1024);
    transpose_w<<<dim3(2048/32, 1024/32), 256, 0, stream>>>(W_kv,     wkv_t,  1024, 2048);
    transpose_w<<<dim3(1024/32, 1024/32), 256, 0, stream>>>(W_out_ca, woca_t, 1024, 1024);
    transpose_w<<<dim3(4096/32, 1024/32), 256, 0, stream>>>(W1,       w1_t,   1024, 4096);
    transpose_w<<<dim3(1024/32, 4096/32), 256, 0, stream>>>(W2,       w2_t,   4096, 1024);

    // --- self-attention block ---
    ln_bf16<<<4096, 256, 0, stream>>>(x, g1, bb1, h_bf);
    gemm_bt<0><<<768, 256, 0, stream>>>(h_bf, wqkv_t, nullptr, qkv_bf, nullptr, nullptr, 4096, 3072, 1024, 24, 8);
    attn_mfma<true><<<dim3(16, 16, 2), 256, 0, stream>>>(qkv_bf, 3072, qkv_bf, 3072, 1024, 2048, y_bf, 2048);
    gemm_bt<2><<<256, 256, 0, stream>>>(y_bf, wosa_t, x1, nullptr, b_out_sa, x, 4096, 1024, 1024, 8, 8);

    // --- cross-attention block ---
    ln_bf16<<<4096, 256, 0, stream>>>(x1, g2, bb2, h_bf);
    gemm_bt<0><<<256, 256, 0, stream>>>(h_bf, wq_t, nullptr, qca_bf, nullptr, nullptr, 4096, 1024, 1024, 8, 8);
    cvt_f32_bf16<<<4096, 256, 0, stream>>>(ctx, hc_bf, 1048576);
    gemm_bt<0><<<512, 256, 0, stream>>>(hc_bf, wkv_t, nullptr, kv_bf, nullptr, nullptr, 4096, 2048, 1024, 16, 8);
    attn_mfma<false><<<dim3(16, 16, 2), 256, 0, stream>>>(qca_bf, 1024, kv_bf, 2048, 0, 1024, y_bf, 2048);
    gemm_bt<2><<<256, 256, 0, stream>>>(y_bf, woca_t, x2, nullptr, b_out_ca, x1, 4096, 1024, 1024, 8, 8);

    // --- MLP block ---
    ln_bf16<<<4096, 256, 0, stream>>>(x2, g3, bb3, h_bf);
    gemm_bt<1><<<1024, 256, 0, stream>>>(h_bf, w1_t, nullptr, m1_bf, b1, nullptr, 4096, 4096, 1024, 32, 8);
    gemm_bt<2><<<256, 256, 0, stream>>>(m1_bf, w2_t, (float*)d_out, nullptr, b2, x2, 4096, 1024, 4096, 8, 2);
}

// Round 15
// 402.493 us; speedup vs baseline: 1.1838x; 1.0257x over previous
//
#include <hip/hip_runtime.h>
#include <hip/hip_bf16.h>

#define D_   1024
#define NH_  16
#define DH_  64
#define T_   2048
#define S_   2048
#define B_   2
#define FF_  4096

typedef __bf16 bf16x8 __attribute__((ext_vector_type(8)));
typedef float  f32x4  __attribute__((ext_vector_type(4)));
typedef unsigned int u32x4 __attribute__((ext_vector_type(4)));

static __device__ __forceinline__ unsigned short f2bf(float f) {
    union { float f; unsigned int i; } v; v.f = f;
    unsigned int x = v.i;
    return (unsigned short)((x + 0x7fffu + ((x >> 16) & 1u)) >> 16);
}
static __device__ __forceinline__ float fexp2(float x) {
    return __builtin_amdgcn_exp2f(x);          // raw v_exp_f32 (fast, 1 VALU op)
}

// async global->LDS, 16B per lane; LDS dest is wave-uniform base + lane*16
static __device__ __forceinline__ void gld16(const unsigned short* g, unsigned short* l) {
    __builtin_amdgcn_global_load_lds(
        (const __attribute__((address_space(1))) void*)g,
        (__attribute__((address_space(3))) void*)l, 16, 0, 0);
}

// ---------------- weight transpose: W[K][N] f32 -> Wt[N][K] bf16 ----------------
__global__ __launch_bounds__(256) void transpose_w(const float* __restrict__ W,
                                                   unsigned short* __restrict__ Wt,
                                                   int K, int N) {
    __shared__ float tile[32][33];
    int n0 = blockIdx.x * 32, k0 = blockIdx.y * 32;
    int c = threadIdx.x & 31, r0 = threadIdx.x >> 5;
    #pragma unroll
    for (int i = 0; i < 4; ++i) {
        int r = r0 + i * 8;
        tile[r][c] = W[(size_t)(k0 + r) * N + n0 + c];
    }
    __syncthreads();
    #pragma unroll
    for (int i = 0; i < 4; ++i) {
        int r = r0 + i * 8;
        Wt[(size_t)(n0 + r) * K + k0 + c] = f2bf(tile[c][r]);
    }
}

// ---------------- LayerNorm (row of 1024 f32) -> bf16 ----------------
__global__ __launch_bounds__(256) void ln_bf16(const float* __restrict__ x,
                                               const float* __restrict__ g,
                                               const float* __restrict__ b,
                                               unsigned short* __restrict__ out) {
    int row = blockIdx.x;
    int t = threadIdx.x;
    const float4* xr = (const float4*)(x + (size_t)row * D_);
    float4 v = xr[t];
    float s = v.x + v.y + v.z + v.w;
    float s2 = v.x*v.x + v.y*v.y + v.z*v.z + v.w*v.w;
    #pragma unroll
    for (int o = 32; o > 0; o >>= 1) { s += __shfl_down(s, o); s2 += __shfl_down(s2, o); }
    __shared__ float red[8];
    int wid = t >> 6, lane = t & 63;
    if (lane == 0) { red[wid*2] = s; red[wid*2+1] = s2; }
    __syncthreads();
    float ts  = red[0] + red[2] + red[4] + red[6];
    float ts2 = red[1] + red[3] + red[5] + red[7];
    float mu = ts * (1.0f / D_);
    float var = ts2 * (1.0f / D_) - mu * mu;
    float rstd = rsqrtf(var + 1e-5f);
    float4 gv = ((const float4*)g)[t];
    float4 bv = ((const float4*)b)[t];
    ushort4 o4;
    o4.x = f2bf((v.x - mu) * rstd * gv.x + bv.x);
    o4.y = f2bf((v.y - mu) * rstd * gv.y + bv.y);
    o4.z = f2bf((v.z - mu) * rstd * gv.z + bv.z);
    o4.w = f2bf((v.w - mu) * rstd * gv.w + bv.w);
    ((ushort4*)(out + (size_t)row * D_))[t] = o4;
}

// ---------------- f32 -> bf16 convert ----------------
__global__ __launch_bounds__(256) void cvt_f32_bf16(const float* __restrict__ in,
                                                    unsigned short* __restrict__ out, int n4) {
    int i = blockIdx.x * 256 + threadIdx.x;
    if (i < n4) {
        float4 v = ((const float4*)in)[i];
        ushort4 o; o.x = f2bf(v.x); o.y = f2bf(v.y); o.z = f2bf(v.z); o.w = f2bf(v.w);
        ((ushort4*)out)[i] = o;
    }
}

// ---------------- split-K reduce: out = part0 + part1 + bias + resid (f32) ----------------
__global__ __launch_bounds__(256) void reduce_splitk2(const float* __restrict__ part,
                                                      const float* __restrict__ bias,
                                                      const float* __restrict__ resid,
                                                      float* __restrict__ out,
                                                      int N, int n4total) {
    int i = blockIdx.x * 256 + threadIdx.x;
    if (i >= n4total) return;
    float4 p0 = ((const float4*)part)[i];
    float4 p1 = ((const float4*)part)[i + n4total];
    float4 rr = ((const float4*)resid)[i];
    int c = (i * 4) & (N - 1);           // N power of two
    float4 o;
    o.x = p0.x + p1.x + rr.x + bias[c];
    o.y = p0.y + p1.y + rr.y + bias[c + 1];
    o.z = p0.z + p1.z + rr.z + bias[c + 2];
    o.w = p0.w + p1.w + rr.w + bias[c + 3];
    ((float4*)out)[i] = o;
}

// ---------------- GEMM: C[M][N] = A[M][K](bf16) @ Bt[N][K]^T (bf16) ----------------
// Round-13 verified structure (L2 rasterization + dbuf + counted vmcnt) + split-K:
// grid = base*kchunks; after the bijective XCD map, kc = wg/base selects the K-slice
// [kc*K/kchunks, ...). EPI=3 writes f32 partials (no epilogue) to Cf + kc*M*N;
// a reduce kernel sums partials + bias + resid. kchunks=1 paths are unchanged.
// EPI 0: bf16 | 1: bf16+bias+relu | 2: f32+bias+resid | 3: f32 partial (split-K)
template<int EPI>
__global__ __launch_bounds__(256) void gemm_bt(const unsigned short* __restrict__ A,
                                               const unsigned short* __restrict__ Bt,
                                               float* __restrict__ Cf,
                                               unsigned short* __restrict__ Cb,
                                               const float* __restrict__ bias,
                                               const float* __restrict__ resid,
                                               int M, int N, int K, int gn, int nb,
                                               int kchunks) {
    __shared__ unsigned short As[2][128 * 32];
    __shared__ unsigned short Bs[2][128 * 32];
    int tid = threadIdx.x;
    int lane = tid & 63, wv = tid >> 6;
    int wm = wv >> 1, wn = wv & 1;
    int lr = lane & 15, lg = lane >> 4;

    int bid = blockIdx.x, nwg = gridDim.x;
    int q8 = nwg >> 3, r8 = nwg & 7;
    int xcd = bid & 7, idx = bid >> 3;
    int wg = (xcd < r8 ? xcd * (q8 + 1) : r8 * (q8 + 1) + (xcd - r8) * q8) + idx;
    int base = nwg / kchunks;
    int kc = wg / base;
    int wg2 = wg - kc * base;
    int gm = base / gn;
    int bandsz = gm * nb;
    int band = wg2 / bandsz;
    int rem = wg2 - band * bandsz;
    int mt = rem / nb;
    int nt = band * nb + (rem - mt * nb);
    int m0 = mt * 128, n0 = nt * 128;
    int Klocal = K / kchunks;
    int koff = kc * Klocal;

    int csw = ((lane & 3) ^ ((lane >> 3) & 3)) * 8;
    const unsigned short* aSrc[2];
    const unsigned short* bSrc[2];
    int dOff[2];
    #pragma unroll
    for (int i = 0; i < 2; ++i) {
        int rblk = wv * 2 + i;
        int row = rblk * 16 + (lane >> 2);
        aSrc[i] = A  + (size_t)(m0 + row) * K + koff + csw;
        bSrc[i] = Bt + (size_t)(n0 + row) * K + koff + csw;
        dOff[i] = rblk * 512;
    }

    const f32x4 vzero = {0.f, 0.f, 0.f, 0.f};
    f32x4 acc[4][4];
    #pragma unroll
    for (int i = 0; i < 4; ++i)
        #pragma unroll
        for (int j = 0; j < 4; ++j) acc[i][j] = vzero;

    const int nsteps = Klocal >> 5;   // Klocal/32

    // prologue: stage K-step 0 into buffer 0 (stays in flight until iter 0's wait)
    #pragma unroll
    for (int i = 0; i < 2; ++i) {
        gld16(aSrc[i], &As[0][dOff[i]]);
        gld16(bSrc[i], &Bs[0][dOff[i]]);
    }

    int cur = 0;
    for (int t = 0; t < nsteps; ++t) {
        if (t + 1 < nsteps) {
            int k0n = (t + 1) << 5;
            #pragma unroll
            for (int i = 0; i < 2; ++i) {
                gld16(aSrc[i] + k0n, &As[cur ^ 1][dOff[i]]);
                gld16(bSrc[i] + k0n, &Bs[cur ^ 1][dOff[i]]);
            }
            asm volatile("s_waitcnt vmcnt(4)" ::: "memory");
        } else {
            asm volatile("s_waitcnt vmcnt(0)" ::: "memory");
        }
        __builtin_amdgcn_s_barrier();
        bf16x8 a[4], b[4];
        #pragma unroll
        for (int f = 0; f < 4; ++f) {
            int ra = wm * 64 + f * 16 + lr;
            a[f] = __builtin_bit_cast(bf16x8, *(const u32x4*)&As[cur][ra * 32 + ((lg ^ ((ra >> 1) & 3)) << 3)]);
            int rb = wn * 64 + f * 16 + lr;
            b[f] = __builtin_bit_cast(bf16x8, *(const u32x4*)&Bs[cur][rb * 32 + ((lg ^ ((rb >> 1) & 3)) << 3)]);
        }
        __builtin_amdgcn_s_setprio(1);
        #pragma unroll
        for (int i = 0; i < 4; ++i)
            #pragma unroll
            for (int j = 0; j < 4; ++j)
                acc[i][j] = __builtin_amdgcn_mfma_f32_16x16x32_bf16(a[i], b[j], acc[i][j], 0, 0, 0);
        __builtin_amdgcn_s_setprio(0);
        __builtin_amdgcn_s_barrier();
        cur ^= 1;
    }

    size_t pbase = (size_t)kc * M * N;
    #pragma unroll
    for (int i = 0; i < 4; ++i) {
        int rbase = m0 + wm * 64 + i * 16 + lg * 4;
        #pragma unroll
        for (int j = 0; j < 4; ++j) {
            int col = n0 + wn * 64 + j * 16 + lr;
            #pragma unroll
            for (int r = 0; r < 4; ++r) {
                int row = rbase + r;
                float v = acc[i][j][r];
                if (EPI == 0) {
                    Cb[(size_t)row * N + col] = f2bf(v);
                } else if (EPI == 1) {
                    v += bias[col];
                    v = v > 0.f ? v : 0.f;
                    Cb[(size_t)row * N + col] = f2bf(v);
                } else if (EPI == 2) {
                    v += bias[col] + resid[(size_t)row * N + col];
                    Cf[(size_t)row * N + col] = v;
                } else {
                    Cf[pbase + (size_t)row * N + col] = v;
                }
            }
        }
    }
}

// ---------------- MFMA flash attention, swapped-QK^T in-register softmax ----------------
// Round-14 verified structure, UNCHANGED. (P in registers, plain-C bf16 pack;
// no P LDS round-trip. kappa key permutation at K-LDS read; sigma swizzle at staging.)
// NOTE: launch_bounds MUST stay (256,2) — higher min-waves spills (r3/r5 evidence).
template<bool CAUSAL>
__global__ __launch_bounds__(256, 2) void attn_mfma(
    const unsigned short* __restrict__ Qsrc, int q_stride,
    const unsigned short* __restrict__ KVsrc, int kv_stride,
    int k_off0, int v_off0,
    unsigned short* __restrict__ Y, int Lk)
{
    __shared__ unsigned short Kl[64 * 64];     // [key][dh], 16B chunk c at c ^ sigma(key)
    __shared__ unsigned short Vt[64 * 64];     // [dh][key], 16B chunk c at c ^ (dh&7)

    const float SCL = 0.125f * 1.44269504f;    // 1/sqrt(DH) * log2(e)

    const int tid = threadIdx.x;
    const int lane = tid & 63, w = tid >> 6;
    const int lr = lane & 15, lg = lane >> 4;
    const int h = blockIdx.y, b = blockIdx.z;
    const int bx = blockIdx.x;

    int qw[2];
    if (CAUSAL) {
        qw[0] = bx * 64 + w * 16;
        qw[1] = (2 * (int)gridDim.x - 1 - bx) * 64 + w * 16;
    } else {
        qw[0] = bx * 128 + w * 16;
        qw[1] = bx * 128 + 64 + w * 16;
    }
    const int ntiles = CAUSAL ? (2 * (int)gridDim.x - bx) : (Lk / 64);

    bf16x8 qf[2][2];
    #pragma unroll
    for (int g = 0; g < 2; ++g) {
        const unsigned short* qp = Qsrc + ((size_t)(b * T_) + qw[g] + lr) * q_stride + h * DH_ + lg * 8;
        qf[g][0] = __builtin_bit_cast(bf16x8, *(const u32x4*)qp);
        qf[g][1] = __builtin_bit_cast(bf16x8, *(const u32x4*)(qp + 32));
    }
    bf16x8 onesf;
    #pragma unroll
    for (int i = 0; i < 8; ++i) onesf[i] = (__bf16)1.0f;

    f32x4 o[2][4];                 // o[g][f][r] = Y[q=lg*4+r][dh=f*16+lr]
    f32x4 accl[2];                 // row-sum, same layout
    float mrow[2];                 // running max (log2 domain) for q = lr
    #pragma unroll
    for (int g = 0; g < 2; ++g) {
        #pragma unroll
        for (int f = 0; f < 4; ++f) o[g][f] = {0.f, 0.f, 0.f, 0.f};
        accl[g] = {0.f, 0.f, 0.f, 0.f};
        mrow[g] = -3e38f;
    }

    // staging thread mappings (block-constant)
    const int kkey = tid >> 2, kdc = (tid & 3) * 2;           // K: 4 threads/key, 2x16B chunks
    const int ksig = (kkey & 3) | (((kkey >> 3) & 1) << 2);   // sigma(key): bits {0,1,3}
    const unsigned short* kbase = KVsrc + ((size_t)(b * Lk) + kkey) * kv_stride + k_off0 + h * DH_ + kdc * 8;
    const int vkey = lane;                                    // V: key per lane; wave w -> dh chunks {w, w+4}
    const unsigned short* vbase = KVsrc + ((size_t)(b * Lk) + vkey) * kv_stride + v_off0 + h * DH_;

    u32x4 kr0 = *(const u32x4*)kbase;
    u32x4 kr1 = *(const u32x4*)(kbase + 8);
    u32x4 vr0 = *(const u32x4*)(vbase + w * 8);
    u32x4 vr1 = *(const u32x4*)(vbase + (w + 4) * 8);

    for (int t = 0; t < ntiles; ++t) {
        const int k0 = t * 64;
        __syncthreads();
        // ---- write staged registers to LDS ----
        {
            int s0 = (kdc    ) ^ ksig;
            int s1 = (kdc + 1) ^ ksig;
            *(u32x4*)&Kl[kkey * 64 + s0 * 8] = kr0;
            *(u32x4*)&Kl[kkey * 64 + s1 * 8] = kr1;
        }
        {
            const unsigned short* u0 = (const unsigned short*)&vr0;
            const unsigned short* u1 = (const unsigned short*)&vr1;
            int khi = vkey >> 3, klo = vkey & 7;
            #pragma unroll
            for (int j = 0; j < 8; ++j) {
                Vt[(w * 8 + j)       * 64 + ((khi ^ j) << 3) + klo] = u0[j];
                Vt[((w + 4) * 8 + j) * 64 + ((khi ^ j) << 3) + klo] = u1[j];
            }
        }
        __syncthreads();
        // ---- prefetch next tile into registers ----
        if (t + 1 < ntiles) {
            const unsigned short* kp = kbase + (size_t)(k0 + 64) * kv_stride;
            kr0 = *(const u32x4*)kp;
            kr1 = *(const u32x4*)(kp + 8);
            const unsigned short* vp = vbase + (size_t)(k0 + 64) * kv_stride;
            vr0 = *(const u32x4*)(vp + w * 8);
            vr1 = *(const u32x4*)(vp + (w + 4) * 8);
        }
        const bool act0 = !CAUSAL || (t <= bx);   // group1 always active

        // ---- QK^T swapped: s[g][f][r] = S[q=lr][key = (f>>1)*32 + lg*8 + (f&1)*4 + r] ----
        f32x4 s[2][4];
        #pragma unroll
        for (int g = 0; g < 2; ++g)
            #pragma unroll
            for (int f = 0; f < 4; ++f) s[g][f] = {0.f, 0.f, 0.f, 0.f};
        __builtin_amdgcn_s_setprio(1);
        #pragma unroll
        for (int ck = 0; ck < 2; ++ck) {
            int kc = lg + 4 * ck;
            #pragma unroll
            for (int f = 0; f < 4; ++f) {
                int krow = ((f >> 1) << 5) + ((lr >> 2) << 3) + ((f & 1) << 2) + (lr & 3);
                bf16x8 kb = __builtin_bit_cast(bf16x8,
                    *(const u32x4*)&Kl[krow * 64 + ((kc ^ (lr & 7)) << 3)]);
                if (act0) s[0][f] = __builtin_amdgcn_mfma_f32_16x16x32_bf16(kb, qf[0][ck], s[0][f], 0, 0, 0);
                s[1][f] = __builtin_amdgcn_mfma_f32_16x16x32_bf16(kb, qf[1][ck], s[1][f], 0, 0, 0);
            }
        }
        __builtin_amdgcn_s_setprio(0);

        // ---- per-group: mask, in-register softmax, P pack (own lane, plain C) ----
        unsigned int pk[2][4][2];
        #pragma unroll
        for (int g = 0; g < 2; ++g) {
            if (g == 0 && !act0) continue;
            if (CAUSAL && (k0 + 63 > qw[g])) {
                int dq = qw[g] + lr - k0 - lg * 8;   // mask if local key part > dq
                #pragma unroll
                for (int f = 0; f < 4; ++f)
                    #pragma unroll
                    for (int r = 0; r < 4; ++r) {
                        int kl = ((f >> 1) << 5) + ((f & 1) << 2) + r;
                        s[g][f][r] = (kl > dq) ? -3e38f : s[g][f][r];
                    }
            }
            float mx = s[g][0][0];
            #pragma unroll
            for (int f = 0; f < 4; ++f)
                #pragma unroll
                for (int r = 0; r < 4; ++r) mx = fmaxf(mx, s[g][f][r]);
            mx = fmaxf(mx, __shfl_xor(mx, 16));
            mx = fmaxf(mx, __shfl_xor(mx, 32));
            float mx2 = mx * SCL;
            if (__any(mx2 > mrow[g] + 8.0f)) {
                float mn = fmaxf(mrow[g], mx2);
                float corrq = fexp2(mrow[g] - mn);
                mrow[g] = mn;
                float co[4];
                #pragma unroll
                for (int r = 0; r < 4; ++r) co[r] = __shfl(corrq, lg * 4 + r);
                #pragma unroll
                for (int f = 0; f < 4; ++f)
                    #pragma unroll
                    for (int r = 0; r < 4; ++r) o[g][f][r] *= co[r];
                #pragma unroll
                for (int r = 0; r < 4; ++r) accl[g][r] *= co[r];
            }
            #pragma unroll
            for (int f = 0; f < 4; ++f)
                #pragma unroll
                for (int wd = 0; wd < 2; ++wd) {
                    float p0 = fexp2(s[g][f][2 * wd    ] * SCL - mrow[g]);
                    float p1 = fexp2(s[g][f][2 * wd + 1] * SCL - mrow[g]);
                    pk[g][f][wd] = ((unsigned int)f2bf(p1) << 16) | (unsigned int)f2bf(p0);
                }
        }

        // ---- PV + row-sum: pa assembled from own registers (no LDS) ----
        __builtin_amdgcn_s_setprio(1);
        #pragma unroll
        for (int ck = 0; ck < 2; ++ck) {
            int kc = lg + 4 * ck;
            bf16x8 pa0, pa1;
            if (act0) {
                u32x4 w0 = {pk[0][2 * ck][0], pk[0][2 * ck][1], pk[0][2 * ck + 1][0], pk[0][2 * ck + 1][1]};
                pa0 = __builtin_bit_cast(bf16x8, w0);
                accl[0] = __builtin_amdgcn_mfma_f32_16x16x32_bf16(pa0, onesf, accl[0], 0, 0, 0);
            }
            u32x4 w1 = {pk[1][2 * ck][0], pk[1][2 * ck][1], pk[1][2 * ck + 1][0], pk[1][2 * ck + 1][1]};
            pa1 = __builtin_bit_cast(bf16x8, w1);
            accl[1] = __builtin_amdgcn_mfma_f32_16x16x32_bf16(pa1, onesf, accl[1], 0, 0, 0);
            #pragma unroll
            for (int f = 0; f < 4; ++f) {
                int dh = f * 16 + lr;
                bf16x8 vb = __builtin_bit_cast(bf16x8,
                    *(const u32x4*)&Vt[dh * 64 + ((kc ^ (dh & 7)) << 3)]);
                if (act0) o[0][f] = __builtin_amdgcn_mfma_f32_16x16x32_bf16(pa0, vb, o[0][f], 0, 0, 0);
                o[1][f] = __builtin_amdgcn_mfma_f32_16x16x32_bf16(pa1, vb, o[1][f], 0, 0, 0);
            }
        }
        __builtin_amdgcn_s_setprio(0);
    }

    // ---- epilogue (both groups) ----
    #pragma unroll
    for (int g = 0; g < 2; ++g) {
        float inv[4];
        #pragma unroll
        for (int r = 0; r < 4; ++r) inv[r] = 1.f / accl[g][r];
        #pragma unroll
        for (int f = 0; f < 4; ++f)
            #pragma unroll
            for (int r = 0; r < 4; ++r) {
                float v = o[g][f][r] * inv[r];
                Y[((size_t)(b * T_) + qw[g] + lg * 4 + r) * D_ + h * DH_ + f * 16 + lr] = f2bf(v);
            }
    }
}

extern "C" void kernel_launch(void* const* d_in, const int* in_sizes, int n_in,
                              void* d_out, int out_size, void* d_ws, size_t ws_size,
                              hipStream_t stream) {
    const float* x        = (const float*)d_in[0];
    const float* ctx      = (const float*)d_in[1];
    const float* W_qkv    = (const float*)d_in[2];
    const float* W_out_sa = (const float*)d_in[3];
    const float* b_out_sa = (const float*)d_in[4];
    const float* W_q      = (const float*)d_in[5];
    const float* W_kv     = (const float*)d_in[6];
    const float* W_out_ca = (const float*)d_in[7];
    const float* b_out_ca = (const float*)d_in[8];
    const float* W1       = (const float*)d_in[9];
    const float* b1       = (const float*)d_in[10];
    const float* W2       = (const float*)d_in[11];
    const float* b2       = (const float*)d_in[12];
    const float* g1  = (const float*)d_in[13];
    const float* bb1 = (const float*)d_in[14];
    const float* g2  = (const float*)d_in[15];
    const float* bb2 = (const float*)d_in[16];
    const float* g3  = (const float*)d_in[17];
    const float* bb3 = (const float*)d_in[18];

    char* ws = (char*)d_ws;
    size_t off = 0;
    auto alloc = [&](size_t bytes) { char* p = ws + off; off += (bytes + 255) & ~(size_t)255; return p; };

    unsigned short* wqkv_t = (unsigned short*)alloc(3072UL * 1024 * 2);
    unsigned short* wosa_t = (unsigned short*)alloc(1024UL * 1024 * 2);
    unsigned short* wq_t   = (unsigned short*)alloc(1024UL * 1024 * 2);
    unsigned short* wkv_t  = (unsigned short*)alloc(2048UL * 1024 * 2);
    unsigned short* woca_t = (unsigned short*)alloc(1024UL * 1024 * 2);
    unsigned short* w1_t   = (unsigned short*)alloc(4096UL * 1024 * 2);
    unsigned short* w2_t   = (unsigned short*)alloc(1024UL * 4096 * 2);
    unsigned short* h_bf   = (unsigned short*)alloc(4096UL * 1024 * 2);
    float*          x1     = (float*)alloc(4096UL * 1024 * 4);
    unsigned short* y_bf   = (unsigned short*)alloc(4096UL * 1024 * 2);
    unsigned short* qkv_bf = (unsigned short*)alloc(4096UL * 3072 * 2);
    unsigned short* qca_bf = (unsigned short*)alloc(4096UL * 1024 * 2);
    unsigned short* kv_bf  = (unsigned short*)alloc(4096UL * 2048 * 2);
    unsigned short* hc_bf  = (unsigned short*)alloc(4096UL * 1024 * 2);
    float*          part   = (float*)alloc(2UL * 4096 * 1024 * 4);   // split-K partials (33.6 MB)
    unsigned short* m1_bf  = qkv_bf;   // reuse: qkv+qca regions dead by MLP
    float* x2 = (float*)d_out;

    // weight transposes (f32 KxN -> bf16 NxK)
    transpose_w<<<dim3(3072/32, 1024/32), 256, 0, stream>>>(W_qkv,    wqkv_t, 1024, 3072);
    transpose_w<<<dim3(1024/32, 1024/32), 256, 0, stream>>>(W_out_sa, wosa_t, 1024, 1024);
    transpose_w<<<dim3(1024/32, 1024/32), 256, 0, stream>>>(W_q,      wq_t,   1024, 1024);
    transpose_w<<<dim3(2048/32, 1024/32), 256, 0, stream>>>(W_kv,     wkv_t,  1024, 2048);
    transpose_w<<<dim3(1024/32, 1024/32), 256, 0, stream>>>(W_out_ca, woca_t, 1024, 1024);
    transpose_w<<<dim3(4096/32, 1024/32), 256, 0, stream>>>(W1,       w1_t,   1024, 4096);
    transpose_w<<<dim3(1024/32, 4096/32), 256, 0, stream>>>(W2,       w2_t,   4096, 1024);

    // --- self-attention block ---
    ln_bf16<<<4096, 256, 0, stream>>>(x, g1, bb1, h_bf);
    gemm_bt<0><<<768, 256, 0, stream>>>(h_bf, wqkv_t, nullptr, qkv_bf, nullptr, nullptr, 4096, 3072, 1024, 24, 8, 1);
    attn_mfma<true><<<dim3(16, 16, 2), 256, 0, stream>>>(qkv_bf, 3072, qkv_bf, 3072, 1024, 2048, y_bf, 2048);
    gemm_bt<3><<<512, 256, 0, stream>>>(y_bf, wosa_t, part, nullptr, nullptr, nullptr, 4096, 1024, 1024, 8, 8, 2);
    reduce_splitk2<<<4096, 256, 0, stream>>>(part, b_out_sa, x, x1, 1024, 1048576);

    // --- cross-attention block ---
    ln_bf16<<<4096, 256, 0, stream>>>(x1, g2, bb2, h_bf);
    gemm_bt<0><<<256, 256, 0, stream>>>(h_bf, wq_t, nullptr, qca_bf, nullptr, nullptr, 4096, 1024, 1024, 8, 8, 1);
    cvt_f32_bf16<<<4096, 256, 0, stream>>>(ctx, hc_bf, 1048576);
    gemm_bt<0><<<512, 256, 0, stream>>>(hc_bf, wkv_t, nullptr, kv_bf, nullptr, nullptr, 4096, 2048, 1024, 16, 8, 1);
    attn_mfma<false><<<dim3(16, 16, 2), 256, 0, stream>>>(qca_bf, 1024, kv_bf, 2048, 0, 1024, y_bf, 2048);
    gemm_bt<3><<<512, 256, 0, stream>>>(y_bf, woca_t, part, nullptr, nullptr, nullptr, 4096, 1024, 1024, 8, 8, 2);
    reduce_splitk2<<<4096, 256, 0, stream>>>(part, b_out_ca, x1, x2, 1024, 1048576);

    // --- MLP block ---
    ln_bf16<<<4096, 256, 0, stream>>>(x2, g3, bb3, h_bf);
    gemm_bt<1><<<1024, 256, 0, stream>>>(h_bf, w1_t, nullptr, m1_bf, b1, nullptr, 4096, 4096, 1024, 32, 8, 1);
    gemm_bt<3><<<512, 256, 0, stream>>>(m1_bf, w2_t, part, nullptr, nullptr, nullptr, 4096, 1024, 4096, 8, 2, 2);
    reduce_splitk2<<<4096, 256, 0, stream>>>(part, b2, x2, (float*)d_out, 1024, 1048576);
}